// Round 4
// baseline (318.682 us; speedup 1.0000x reference)
//
#include <hip/hip_runtime.h>
#include <hip/hip_bf16.h>

#define N_NODES 50000
#define N_EDGES 800000
#define SCAN_NBLK ((N_NODES + 255) / 256)   // 196

// ---------------------------------------------------------------------------
// GEMM1: support1[50000][96] = x[50000][256] @ W1[256][96]   (f32 vector)
// 64-row x 96-col tile, 256 threads, per-thread 4x6. 782 blocks (~3/CU).
// ---------------------------------------------------------------------------
__global__ __launch_bounds__(256) void gemm1_kernel(const float* __restrict__ x,
                                                    const float* __restrict__ W1,
                                                    float* __restrict__ out) {
    __shared__ float xs[64][33];
    __shared__ float ws[32][96];
    const int tid = threadIdx.x;
    const int block_row = blockIdx.x * 64;
    const int tc = tid & 15;
    const int tr = tid >> 4;
    const int c0 = tc * 6;
    const int r0 = tr * 4;
    float acc[4][6];
    #pragma unroll
    for (int i = 0; i < 4; ++i)
        #pragma unroll
        for (int j = 0; j < 6; ++j) acc[i][j] = 0.f;

    const int lr = tid >> 3;          // 0..31
    const int kq = (tid & 7) * 4;     // 0..28

    for (int k0 = 0; k0 < 256; k0 += 32) {
        #pragma unroll
        for (int it = 0; it < 2; ++it) {
            int row  = lr + it * 32;
            int grow = block_row + row;
            float4 v = make_float4(0.f, 0.f, 0.f, 0.f);
            if (grow < N_NODES)
                v = *reinterpret_cast<const float4*>(&x[(size_t)grow * 256 + k0 + kq]);
            xs[row][kq]     = v.x;
            xs[row][kq + 1] = v.y;
            xs[row][kq + 2] = v.z;
            xs[row][kq + 3] = v.w;
        }
        {
            const float4* wsrc = reinterpret_cast<const float4*>(W1 + k0 * 96);
            float4* wdst = reinterpret_cast<float4*>(&ws[0][0]);
            #pragma unroll
            for (int i = 0; i < 3; ++i) wdst[tid + i * 256] = wsrc[tid + i * 256];
        }
        __syncthreads();
        #pragma unroll 4
        for (int kk = 0; kk < 32; ++kk) {
            float a[4], b[6];
            #pragma unroll
            for (int i = 0; i < 4; ++i) a[i] = xs[r0 + i][kk];
            #pragma unroll
            for (int j = 0; j < 6; ++j) b[j] = ws[kk][c0 + j];
            #pragma unroll
            for (int i = 0; i < 4; ++i)
                #pragma unroll
                for (int j = 0; j < 6; ++j) acc[i][j] += a[i] * b[j];
        }
        __syncthreads();
    }
    #pragma unroll
    for (int i = 0; i < 4; ++i) {
        int grow = block_row + r0 + i;
        if (grow < N_NODES) {
            float* o = &out[(size_t)grow * 96 + c0];
            #pragma unroll
            for (int j = 0; j < 6; ++j) o[j] = acc[i][j];
        }
    }
}

// ---------------------------------------------------------------------------
// GEMM2: support2[50000][64] = h1[50000][96] @ W2[96][64]
// 64-row x 64-col tile, 256 threads, per-thread 4x4. 782 blocks.
// ---------------------------------------------------------------------------
__global__ __launch_bounds__(256) void gemm2_kernel(const float* __restrict__ h,
                                                    const float* __restrict__ W2,
                                                    float* __restrict__ out) {
    __shared__ float xs[64][33];
    __shared__ float ws[32][64];
    const int tid = threadIdx.x;
    const int block_row = blockIdx.x * 64;
    const int tc = tid & 15;
    const int tr = tid >> 4;
    const int c0 = tc * 4;
    const int r0 = tr * 4;
    float acc[4][4];
    #pragma unroll
    for (int i = 0; i < 4; ++i)
        #pragma unroll
        for (int j = 0; j < 4; ++j) acc[i][j] = 0.f;

    const int lr = tid >> 3;
    const int kq = (tid & 7) * 4;

    for (int k0 = 0; k0 < 96; k0 += 32) {
        #pragma unroll
        for (int it = 0; it < 2; ++it) {
            int row  = lr + it * 32;
            int grow = block_row + row;
            float4 v = make_float4(0.f, 0.f, 0.f, 0.f);
            if (grow < N_NODES)
                v = *reinterpret_cast<const float4*>(&h[(size_t)grow * 96 + k0 + kq]);
            xs[row][kq]     = v.x;
            xs[row][kq + 1] = v.y;
            xs[row][kq + 2] = v.z;
            xs[row][kq + 3] = v.w;
        }
        {
            const float4* wsrc = reinterpret_cast<const float4*>(W2 + k0 * 64);
            float4* wdst = reinterpret_cast<float4*>(&ws[0][0]);
            #pragma unroll
            for (int i = 0; i < 2; ++i) wdst[tid + i * 256] = wsrc[tid + i * 256];
        }
        __syncthreads();
        #pragma unroll 4
        for (int kk = 0; kk < 32; ++kk) {
            float a[4], b[4];
            #pragma unroll
            for (int i = 0; i < 4; ++i) a[i] = xs[r0 + i][kk];
            #pragma unroll
            for (int j = 0; j < 4; ++j) b[j] = ws[kk][c0 + j];
            #pragma unroll
            for (int i = 0; i < 4; ++i)
                #pragma unroll
                for (int j = 0; j < 4; ++j) acc[i][j] += a[i] * b[j];
        }
        __syncthreads();
    }
    #pragma unroll
    for (int i = 0; i < 4; ++i) {
        int grow = block_row + r0 + i;
        if (grow < N_NODES) {
            float4 v = make_float4(acc[i][0], acc[i][1], acc[i][2], acc[i][3]);
            *reinterpret_cast<float4*>(&out[(size_t)grow * 64 + c0]) = v;
        }
    }
}

// ---------------------------------------------------------------------------
// CSR build step 1: histogram of dst
// ---------------------------------------------------------------------------
__global__ __launch_bounds__(256) void hist_kernel(const int* __restrict__ dstv,
                                                   int* __restrict__ cnt) {
    int e = blockIdx.x * 256 + threadIdx.x;
    if (e < N_EDGES) atomicAdd(&cnt[dstv[e]], 1);
}

// ---------------------------------------------------------------------------
// Multi-block exclusive scan of cnt[50000] -> off[50001] (+ cursor copy).
// ---------------------------------------------------------------------------
__global__ __launch_bounds__(256) void scan1_kernel(const int* __restrict__ cnt,
                                                    int* __restrict__ bsum) {
    __shared__ int red[256];
    const int t = threadIdx.x;
    const int i = blockIdx.x * 256 + t;
    red[t] = (i < N_NODES) ? cnt[i] : 0;
    __syncthreads();
    #pragma unroll
    for (int d = 128; d > 0; d >>= 1) {
        if (t < d) red[t] += red[t + d];
        __syncthreads();
    }
    if (t == 0) bsum[blockIdx.x] = red[0];
}

__global__ __launch_bounds__(256) void scan2_kernel(int* __restrict__ bsum) {
    __shared__ int sh[256];
    const int t = threadIdx.x;
    int v = (t < SCAN_NBLK) ? bsum[t] : 0;
    sh[t] = v;
    __syncthreads();
    #pragma unroll
    for (int d = 1; d < 256; d <<= 1) {
        int u = (t >= d) ? sh[t - d] : 0;
        __syncthreads();
        sh[t] += u;
        __syncthreads();
    }
    if (t < SCAN_NBLK) bsum[t] = sh[t] - v;
}

__global__ __launch_bounds__(256) void scan3_kernel(const int* __restrict__ cnt,
                                                    const int* __restrict__ bsum,
                                                    int* __restrict__ off,
                                                    int* __restrict__ cur) {
    __shared__ int sh[256];
    const int t = threadIdx.x;
    const int i = blockIdx.x * 256 + t;
    int v = (i < N_NODES) ? cnt[i] : 0;
    sh[t] = v;
    __syncthreads();
    #pragma unroll
    for (int d = 1; d < 256; d <<= 1) {
        int u = (t >= d) ? sh[t - d] : 0;
        __syncthreads();
        sh[t] += u;
        __syncthreads();
    }
    int excl = sh[t] - v + bsum[blockIdx.x];
    if (i < N_NODES) {
        off[i] = excl;
        cur[i] = excl;
    }
    if (i == N_NODES - 1) off[N_NODES] = excl + v;
}

// ---------------------------------------------------------------------------
// CSR build step 3: fill packed (src, weight_bits) per edge, grouped by dst.
// ---------------------------------------------------------------------------
__global__ __launch_bounds__(256) void fill_kernel(const int* __restrict__ srcv,
                                                   const int* __restrict__ dstv,
                                                   const float* __restrict__ wv,
                                                   int* __restrict__ cur,
                                                   int2* __restrict__ ewp) {
    int e = blockIdx.x * 256 + threadIdx.x;
    if (e >= N_EDGES) return;
    int d = dstv[e];
    int pos = atomicAdd(&cur[d], 1);
    ewp[pos] = make_int2(srcv[e], __float_as_int(wv[e]));
}

// ---------------------------------------------------------------------------
// Layer-1 gather aggregation: out[n][:] = relu( sum sup[src]*w + b1 )
// ---------------------------------------------------------------------------
template <int DIM>
__global__ __launch_bounds__(256) void gather_agg_kernel(const float* __restrict__ sup,
                                                         const int* __restrict__ off,
                                                         const int2* __restrict__ ewp,
                                                         const float* __restrict__ bias,
                                                         float* __restrict__ outp) {
    const int NQ = DIM / 4;
    unsigned gid = blockIdx.x * 256u + threadIdx.x;
    if (gid >= (unsigned)N_NODES * NQ) return;
    unsigned n = gid / NQ;
    unsigned q = gid - n * NQ;
    const int e0 = off[n], e1 = off[n + 1];
    float4 acc = make_float4(0.f, 0.f, 0.f, 0.f);
    for (int e = e0; e < e1; ++e) {
        int2 p = ewp[e];
        float w = __int_as_float(p.y);
        float4 v = *reinterpret_cast<const float4*>(&sup[(size_t)p.x * DIM + q * 4]);
        acc.x += v.x * w;
        acc.y += v.y * w;
        acc.z += v.z * w;
        acc.w += v.w * w;
    }
    const float4 bb = *reinterpret_cast<const float4*>(&bias[q * 4]);
    acc.x = fmaxf(acc.x + bb.x, 0.f);
    acc.y = fmaxf(acc.y + bb.y, 0.f);
    acc.z = fmaxf(acc.z + bb.z, 0.f);
    acc.w = fmaxf(acc.w + bb.w, 0.f);
    *reinterpret_cast<float4*>(&outp[(size_t)n * DIM + q * 4]) = acc;
}

// ---------------------------------------------------------------------------
// Layer-2 gather + mean-pool fusion (h2 never materialized):
// per (node, quad): acc = relu(sum sup2[src]*w + b2); reduce columns in LDS;
// one atomicAdd per channel per block into pooled[64].
// 50000 nodes * 16 quads = 800000 threads = 3125 blocks of 256 (16 nodes/blk).
// ---------------------------------------------------------------------------
__global__ __launch_bounds__(256) void gather_pool_kernel(const float* __restrict__ sup,
                                                          const int* __restrict__ off,
                                                          const int2* __restrict__ ewp,
                                                          const float* __restrict__ bias,
                                                          float* __restrict__ pooled) {
    __shared__ float red[16][64];
    const int t = threadIdx.x;
    unsigned gid = blockIdx.x * 256u + t;
    unsigned n = gid >> 4;          // 16 quads per node
    unsigned q = gid & 15;
    const int e0 = off[n], e1 = off[n + 1];
    float4 acc = make_float4(0.f, 0.f, 0.f, 0.f);
    for (int e = e0; e < e1; ++e) {
        int2 p = ewp[e];
        float w = __int_as_float(p.y);
        float4 v = *reinterpret_cast<const float4*>(&sup[(size_t)p.x * 64 + q * 4]);
        acc.x += v.x * w;
        acc.y += v.y * w;
        acc.z += v.z * w;
        acc.w += v.w * w;
    }
    const float4 bb = *reinterpret_cast<const float4*>(&bias[q * 4]);
    const int nl = t >> 4;          // node-local index 0..15
    red[nl][q * 4 + 0] = fmaxf(acc.x + bb.x, 0.f);
    red[nl][q * 4 + 1] = fmaxf(acc.y + bb.y, 0.f);
    red[nl][q * 4 + 2] = fmaxf(acc.z + bb.z, 0.f);
    red[nl][q * 4 + 3] = fmaxf(acc.w + bb.w, 0.f);
    __syncthreads();
    if (t < 64) {
        float s = 0.f;
        #pragma unroll
        for (int r = 0; r < 16; ++r) s += red[r][t];
        unsafeAtomicAdd(&pooled[t], s);
    }
}

// ---------------------------------------------------------------------------
// Final head: selu(pooled/N) + 0.5*(sub_fea @ fc_w^T + fc_b) -> log_softmax
// ---------------------------------------------------------------------------
__global__ void final_kernel(const float* __restrict__ pooled,
                             const float* __restrict__ sub_fea,
                             const float* __restrict__ fc_w,
                             const float* __restrict__ fc_b,
                             float* __restrict__ out) {
    const int c = threadIdx.x;  // 0..63
    float p = pooled[c] * (1.0f / (float)N_NODES);
    const float kScale = 1.0507009873554805f;
    const float kAlpha = 1.6732632423543772f;
    float se = (p > 0.f) ? kScale * p : kScale * kAlpha * (expf(p) - 1.f);
    float xe = fc_b[c];
    for (int k = 0; k < 128; ++k) xe += sub_fea[k] * fc_w[c * 128 + k];
    float v = se + 0.5f * xe;
    float m = v;
    #pragma unroll
    for (int off = 32; off >= 1; off >>= 1) m = fmaxf(m, __shfl_xor(m, off));
    float ex = expf(v - m);
    float ss = ex;
    #pragma unroll
    for (int off = 32; off >= 1; off >>= 1) ss += __shfl_xor(ss, off);
    out[c] = v - m - logf(ss);
}

// ---------------------------------------------------------------------------
extern "C" void kernel_launch(void* const* d_in, const int* in_sizes, int n_in,
                              void* d_out, int out_size, void* d_ws, size_t ws_size,
                              hipStream_t stream) {
    const float* x       = (const float*)d_in[0];
    const int*   ei      = (const int*)d_in[1];   // [2][E]: src row 0, dst row 1
    const float* ew      = (const float*)d_in[2];
    const float* sub_fea = (const float*)d_in[3];
    const float* W1      = (const float*)d_in[4];
    const float* b1      = (const float*)d_in[5];
    const float* W2      = (const float*)d_in[6];
    const float* b2      = (const float*)d_in[7];
    const float* fc_w    = (const float*)d_in[8];
    const float* fc_b    = (const float*)d_in[9];
    float* out = (float*)d_out;

    // Workspace layout (bytes). A reused: support1 then support2. B: h1.
    char* base = (char*)d_ws;
    float* A      = (float*)(base);                 // 4.8M floats (19.2 MB)
    float* B      = (float*)(base + 19200000);      // 4.8M floats (19.2 MB)
    float* pooled = (float*)(base + 38400000);      // 64 floats
    int*   off    = (int*)  (base + 38400512);      // 50001 ints
    int*   cnt    = (int*)  (base + 38600960);      // 50000 ints
    int*   cur    = (int*)  (base + 38801408);      // 50000 ints
    int*   bsum   = (int*)  (base + 39001856);      // 256 ints
    int2*  ewp    = (int2*) (base + 39002880);      // 800000 int2 (6.4 MB)

    const int* srcv = ei;
    const int* dstv = ei + N_EDGES;

    // ---- CSR build (shared by both layers) ----
    hipMemsetAsync(cnt, 0, N_NODES * 4, stream);
    hipMemsetAsync(pooled, 0, 64 * 4, stream);
    hist_kernel<<<(N_EDGES + 255) / 256, 256, 0, stream>>>(dstv, cnt);
    scan1_kernel<<<SCAN_NBLK, 256, 0, stream>>>(cnt, bsum);
    scan2_kernel<<<1, 256, 0, stream>>>(bsum);
    scan3_kernel<<<SCAN_NBLK, 256, 0, stream>>>(cnt, bsum, off, cur);
    fill_kernel<<<(N_EDGES + 255) / 256, 256, 0, stream>>>(srcv, dstv, ew, cur, ewp);

    // ---- Layer 1 ----
    gemm1_kernel<<<(N_NODES + 63) / 64, 256, 0, stream>>>(x, W1, A);
    {
        unsigned total = (unsigned)N_NODES * 24;
        gather_agg_kernel<96><<<(total + 255) / 256, 256, 0, stream>>>(A, off, ewp, b1, B);
    }

    // ---- Layer 2 ----
    gemm2_kernel<<<(N_NODES + 63) / 64, 256, 0, stream>>>(B, W2, A);
    gather_pool_kernel<<<(N_NODES * 16) / 256, 256, 0, stream>>>(A, off, ewp, b2, pooled);

    // ---- Head ----
    final_kernel<<<1, 64, 0, stream>>>(pooled, sub_fea, fc_w, fc_b, out);
}

// Round 5
// 259.007 us; speedup vs baseline: 1.2304x; 1.2304x over previous
//
#include <hip/hip_runtime.h>
#include <hip/hip_bf16.h>

#define N_NODES 50000
#define N_EDGES 800000
#define SCAN_NBLK ((N_NODES + 255) / 256)   // 196

// ---------------------------------------------------------------------------
// GEMM1: support1[50000][96] = x[50000][256] @ W1[256][96]   (f32 vector)
// 64-row x 96-col tile, 256 threads, per-thread 4x6. 782 blocks (~3/CU).
// ---------------------------------------------------------------------------
__global__ __launch_bounds__(256) void gemm1_kernel(const float* __restrict__ x,
                                                    const float* __restrict__ W1,
                                                    float* __restrict__ out) {
    __shared__ float xs[64][33];
    __shared__ float ws[32][96];
    const int tid = threadIdx.x;
    const int block_row = blockIdx.x * 64;
    const int tc = tid & 15;
    const int tr = tid >> 4;
    const int c0 = tc * 6;
    const int r0 = tr * 4;
    float acc[4][6];
    #pragma unroll
    for (int i = 0; i < 4; ++i)
        #pragma unroll
        for (int j = 0; j < 6; ++j) acc[i][j] = 0.f;

    const int lr = tid >> 3;          // 0..31
    const int kq = (tid & 7) * 4;     // 0..28

    for (int k0 = 0; k0 < 256; k0 += 32) {
        #pragma unroll
        for (int it = 0; it < 2; ++it) {
            int row  = lr + it * 32;
            int grow = block_row + row;
            float4 v = make_float4(0.f, 0.f, 0.f, 0.f);
            if (grow < N_NODES)
                v = *reinterpret_cast<const float4*>(&x[(size_t)grow * 256 + k0 + kq]);
            xs[row][kq]     = v.x;
            xs[row][kq + 1] = v.y;
            xs[row][kq + 2] = v.z;
            xs[row][kq + 3] = v.w;
        }
        {
            const float4* wsrc = reinterpret_cast<const float4*>(W1 + k0 * 96);
            float4* wdst = reinterpret_cast<float4*>(&ws[0][0]);
            #pragma unroll
            for (int i = 0; i < 3; ++i) wdst[tid + i * 256] = wsrc[tid + i * 256];
        }
        __syncthreads();
        #pragma unroll 4
        for (int kk = 0; kk < 32; ++kk) {
            float a[4], b[6];
            #pragma unroll
            for (int i = 0; i < 4; ++i) a[i] = xs[r0 + i][kk];
            #pragma unroll
            for (int j = 0; j < 6; ++j) b[j] = ws[kk][c0 + j];
            #pragma unroll
            for (int i = 0; i < 4; ++i)
                #pragma unroll
                for (int j = 0; j < 6; ++j) acc[i][j] += a[i] * b[j];
        }
        __syncthreads();
    }
    #pragma unroll
    for (int i = 0; i < 4; ++i) {
        int grow = block_row + r0 + i;
        if (grow < N_NODES) {
            float* o = &out[(size_t)grow * 96 + c0];
            #pragma unroll
            for (int j = 0; j < 6; ++j) o[j] = acc[i][j];
        }
    }
}

// ---------------------------------------------------------------------------
// GEMM2: support2[50000][64] = h1[50000][96] @ W2[96][64]
// 64-row x 64-col tile, 256 threads, per-thread 4x4. 782 blocks.
// ---------------------------------------------------------------------------
__global__ __launch_bounds__(256) void gemm2_kernel(const float* __restrict__ h,
                                                    const float* __restrict__ W2,
                                                    float* __restrict__ out) {
    __shared__ float xs[64][33];
    __shared__ float ws[32][64];
    const int tid = threadIdx.x;
    const int block_row = blockIdx.x * 64;
    const int tc = tid & 15;
    const int tr = tid >> 4;
    const int c0 = tc * 4;
    const int r0 = tr * 4;
    float acc[4][4];
    #pragma unroll
    for (int i = 0; i < 4; ++i)
        #pragma unroll
        for (int j = 0; j < 4; ++j) acc[i][j] = 0.f;

    const int lr = tid >> 3;
    const int kq = (tid & 7) * 4;

    for (int k0 = 0; k0 < 96; k0 += 32) {
        #pragma unroll
        for (int it = 0; it < 2; ++it) {
            int row  = lr + it * 32;
            int grow = block_row + row;
            float4 v = make_float4(0.f, 0.f, 0.f, 0.f);
            if (grow < N_NODES)
                v = *reinterpret_cast<const float4*>(&h[(size_t)grow * 96 + k0 + kq]);
            xs[row][kq]     = v.x;
            xs[row][kq + 1] = v.y;
            xs[row][kq + 2] = v.z;
            xs[row][kq + 3] = v.w;
        }
        {
            const float4* wsrc = reinterpret_cast<const float4*>(W2 + k0 * 64);
            float4* wdst = reinterpret_cast<float4*>(&ws[0][0]);
            #pragma unroll
            for (int i = 0; i < 2; ++i) wdst[tid + i * 256] = wsrc[tid + i * 256];
        }
        __syncthreads();
        #pragma unroll 4
        for (int kk = 0; kk < 32; ++kk) {
            float a[4], b[4];
            #pragma unroll
            for (int i = 0; i < 4; ++i) a[i] = xs[r0 + i][kk];
            #pragma unroll
            for (int j = 0; j < 4; ++j) b[j] = ws[kk][c0 + j];
            #pragma unroll
            for (int i = 0; i < 4; ++i)
                #pragma unroll
                for (int j = 0; j < 4; ++j) acc[i][j] += a[i] * b[j];
        }
        __syncthreads();
    }
    #pragma unroll
    for (int i = 0; i < 4; ++i) {
        int grow = block_row + r0 + i;
        if (grow < N_NODES) {
            float4 v = make_float4(acc[i][0], acc[i][1], acc[i][2], acc[i][3]);
            *reinterpret_cast<float4*>(&out[(size_t)grow * 64 + c0]) = v;
        }
    }
}

// ---------------------------------------------------------------------------
// CSR build step 1: histogram of dst
// ---------------------------------------------------------------------------
__global__ __launch_bounds__(256) void hist_kernel(const int* __restrict__ dstv,
                                                   int* __restrict__ cnt) {
    int e = blockIdx.x * 256 + threadIdx.x;
    if (e < N_EDGES) atomicAdd(&cnt[dstv[e]], 1);
}

// ---------------------------------------------------------------------------
// Multi-block exclusive scan of cnt[50000] -> off[50001] (+ cursor copy).
// ---------------------------------------------------------------------------
__global__ __launch_bounds__(256) void scan1_kernel(const int* __restrict__ cnt,
                                                    int* __restrict__ bsum) {
    __shared__ int red[256];
    const int t = threadIdx.x;
    const int i = blockIdx.x * 256 + t;
    red[t] = (i < N_NODES) ? cnt[i] : 0;
    __syncthreads();
    #pragma unroll
    for (int d = 128; d > 0; d >>= 1) {
        if (t < d) red[t] += red[t + d];
        __syncthreads();
    }
    if (t == 0) bsum[blockIdx.x] = red[0];
}

__global__ __launch_bounds__(256) void scan2_kernel(int* __restrict__ bsum) {
    __shared__ int sh[256];
    const int t = threadIdx.x;
    int v = (t < SCAN_NBLK) ? bsum[t] : 0;
    sh[t] = v;
    __syncthreads();
    #pragma unroll
    for (int d = 1; d < 256; d <<= 1) {
        int u = (t >= d) ? sh[t - d] : 0;
        __syncthreads();
        sh[t] += u;
        __syncthreads();
    }
    if (t < SCAN_NBLK) bsum[t] = sh[t] - v;
}

__global__ __launch_bounds__(256) void scan3_kernel(const int* __restrict__ cnt,
                                                    const int* __restrict__ bsum,
                                                    int* __restrict__ off,
                                                    int* __restrict__ cur) {
    __shared__ int sh[256];
    const int t = threadIdx.x;
    const int i = blockIdx.x * 256 + t;
    int v = (i < N_NODES) ? cnt[i] : 0;
    sh[t] = v;
    __syncthreads();
    #pragma unroll
    for (int d = 1; d < 256; d <<= 1) {
        int u = (t >= d) ? sh[t - d] : 0;
        __syncthreads();
        sh[t] += u;
        __syncthreads();
    }
    int excl = sh[t] - v + bsum[blockIdx.x];
    if (i < N_NODES) {
        off[i] = excl;
        cur[i] = excl;
    }
    if (i == N_NODES - 1) off[N_NODES] = excl + v;
}

// ---------------------------------------------------------------------------
// CSR build step 3: fill packed (src, weight_bits) per edge, grouped by dst.
// ---------------------------------------------------------------------------
__global__ __launch_bounds__(256) void fill_kernel(const int* __restrict__ srcv,
                                                   const int* __restrict__ dstv,
                                                   const float* __restrict__ wv,
                                                   int* __restrict__ cur,
                                                   int2* __restrict__ ewp) {
    int e = blockIdx.x * 256 + threadIdx.x;
    if (e >= N_EDGES) return;
    int d = dstv[e];
    int pos = atomicAdd(&cur[d], 1);
    ewp[pos] = make_int2(srcv[e], __float_as_int(wv[e]));
}

// ---------------------------------------------------------------------------
// Gather aggregation, 4x-unrolled for MLP:
// out[n][:] = relu( sum_{e in row n} sup[src_e]*w_e + b )
// One thread per (node, channel-quad). 4 independent accumulators so the
// 4 ewp loads + 4 sup gathers per iteration are all in flight together.
// ---------------------------------------------------------------------------
template <int DIM>
__global__ __launch_bounds__(256) void gather_agg_kernel(const float* __restrict__ sup,
                                                         const int* __restrict__ off,
                                                         const int2* __restrict__ ewp,
                                                         const float* __restrict__ bias,
                                                         float* __restrict__ outp) {
    const int NQ = DIM / 4;
    unsigned gid = blockIdx.x * 256u + threadIdx.x;
    if (gid >= (unsigned)N_NODES * NQ) return;
    unsigned n = gid / NQ;
    unsigned q = gid - n * NQ;
    const int e0 = off[n], e1 = off[n + 1];
    float4 a0 = make_float4(0.f, 0.f, 0.f, 0.f);
    float4 a1 = make_float4(0.f, 0.f, 0.f, 0.f);
    float4 a2 = make_float4(0.f, 0.f, 0.f, 0.f);
    float4 a3 = make_float4(0.f, 0.f, 0.f, 0.f);
    int e = e0;
    for (; e + 4 <= e1; e += 4) {
        int2 p0 = ewp[e];
        int2 p1 = ewp[e + 1];
        int2 p2 = ewp[e + 2];
        int2 p3 = ewp[e + 3];
        float4 v0 = *reinterpret_cast<const float4*>(&sup[(size_t)p0.x * DIM + q * 4]);
        float4 v1 = *reinterpret_cast<const float4*>(&sup[(size_t)p1.x * DIM + q * 4]);
        float4 v2 = *reinterpret_cast<const float4*>(&sup[(size_t)p2.x * DIM + q * 4]);
        float4 v3 = *reinterpret_cast<const float4*>(&sup[(size_t)p3.x * DIM + q * 4]);
        float w0 = __int_as_float(p0.y);
        float w1 = __int_as_float(p1.y);
        float w2 = __int_as_float(p2.y);
        float w3 = __int_as_float(p3.y);
        a0.x += v0.x * w0; a0.y += v0.y * w0; a0.z += v0.z * w0; a0.w += v0.w * w0;
        a1.x += v1.x * w1; a1.y += v1.y * w1; a1.z += v1.z * w1; a1.w += v1.w * w1;
        a2.x += v2.x * w2; a2.y += v2.y * w2; a2.z += v2.z * w2; a2.w += v2.w * w2;
        a3.x += v3.x * w3; a3.y += v3.y * w3; a3.z += v3.z * w3; a3.w += v3.w * w3;
    }
    for (; e < e1; ++e) {
        int2 p = ewp[e];
        float w = __int_as_float(p.y);
        float4 v = *reinterpret_cast<const float4*>(&sup[(size_t)p.x * DIM + q * 4]);
        a0.x += v.x * w; a0.y += v.y * w; a0.z += v.z * w; a0.w += v.w * w;
    }
    a0.x += a1.x + a2.x + a3.x;
    a0.y += a1.y + a2.y + a3.y;
    a0.z += a1.z + a2.z + a3.z;
    a0.w += a1.w + a2.w + a3.w;
    const float4 bb = *reinterpret_cast<const float4*>(&bias[q * 4]);
    a0.x = fmaxf(a0.x + bb.x, 0.f);
    a0.y = fmaxf(a0.y + bb.y, 0.f);
    a0.z = fmaxf(a0.z + bb.z, 0.f);
    a0.w = fmaxf(a0.w + bb.w, 0.f);
    *reinterpret_cast<float4*>(&outp[(size_t)n * DIM + q * 4]) = a0;
}

// ---------------------------------------------------------------------------
// Column-sum of h2 (already bias+relu'd) over all nodes -> pooled[64]
// ---------------------------------------------------------------------------
__global__ __launch_bounds__(256) void colsum_kernel(const float* __restrict__ h2,
                                                     float* __restrict__ pooled) {
    __shared__ float red[4][64];
    const int t = threadIdx.x;
    const int c = t & 63, r = t >> 6;
    float s = 0.f;
    const int base = blockIdx.x * 256;
    for (int i = r; i < 256; i += 4) {
        int n = base + i;
        if (n < N_NODES) s += h2[(size_t)n * 64 + c];
    }
    red[r][c] = s;
    __syncthreads();
    if (r == 0) {
        float v = red[0][c] + red[1][c] + red[2][c] + red[3][c];
        unsafeAtomicAdd(&pooled[c], v);
    }
}

// ---------------------------------------------------------------------------
// Final head: selu(pooled/N) + 0.5*(sub_fea @ fc_w^T + fc_b) -> log_softmax
// ---------------------------------------------------------------------------
__global__ void final_kernel(const float* __restrict__ pooled,
                             const float* __restrict__ sub_fea,
                             const float* __restrict__ fc_w,
                             const float* __restrict__ fc_b,
                             float* __restrict__ out) {
    const int c = threadIdx.x;  // 0..63
    float p = pooled[c] * (1.0f / (float)N_NODES);
    const float kScale = 1.0507009873554805f;
    const float kAlpha = 1.6732632423543772f;
    float se = (p > 0.f) ? kScale * p : kScale * kAlpha * (expf(p) - 1.f);
    float xe = fc_b[c];
    for (int k = 0; k < 128; ++k) xe += sub_fea[k] * fc_w[c * 128 + k];
    float v = se + 0.5f * xe;
    float m = v;
    #pragma unroll
    for (int off = 32; off >= 1; off >>= 1) m = fmaxf(m, __shfl_xor(m, off));
    float ex = expf(v - m);
    float ss = ex;
    #pragma unroll
    for (int off = 32; off >= 1; off >>= 1) ss += __shfl_xor(ss, off);
    out[c] = v - m - logf(ss);
}

// ---------------------------------------------------------------------------
extern "C" void kernel_launch(void* const* d_in, const int* in_sizes, int n_in,
                              void* d_out, int out_size, void* d_ws, size_t ws_size,
                              hipStream_t stream) {
    const float* x       = (const float*)d_in[0];
    const int*   ei      = (const int*)d_in[1];   // [2][E]: src row 0, dst row 1
    const float* ew      = (const float*)d_in[2];
    const float* sub_fea = (const float*)d_in[3];
    const float* W1      = (const float*)d_in[4];
    const float* b1      = (const float*)d_in[5];
    const float* W2      = (const float*)d_in[6];
    const float* b2      = (const float*)d_in[7];
    const float* fc_w    = (const float*)d_in[8];
    const float* fc_b    = (const float*)d_in[9];
    float* out = (float*)d_out;

    // Workspace layout (bytes). A reused: support1 then support2. B: h1 then h2.
    char* base = (char*)d_ws;
    float* A      = (float*)(base);                 // 4.8M floats (19.2 MB)
    float* B      = (float*)(base + 19200000);      // 4.8M floats (19.2 MB)
    float* pooled = (float*)(base + 38400000);      // 64 floats
    int*   off    = (int*)  (base + 38400512);      // 50001 ints
    int*   cnt    = (int*)  (base + 38600960);      // 50000 ints
    int*   cur    = (int*)  (base + 38801408);      // 50000 ints
    int*   bsum   = (int*)  (base + 39001856);      // 256 ints
    int2*  ewp    = (int2*) (base + 39002880);      // 800000 int2 (6.4 MB)

    const int* srcv = ei;
    const int* dstv = ei + N_EDGES;

    // ---- CSR build (shared by both layers) ----
    hipMemsetAsync(cnt, 0, N_NODES * 4, stream);
    hipMemsetAsync(pooled, 0, 64 * 4, stream);
    hist_kernel<<<(N_EDGES + 255) / 256, 256, 0, stream>>>(dstv, cnt);
    scan1_kernel<<<SCAN_NBLK, 256, 0, stream>>>(cnt, bsum);
    scan2_kernel<<<1, 256, 0, stream>>>(bsum);
    scan3_kernel<<<SCAN_NBLK, 256, 0, stream>>>(cnt, bsum, off, cur);
    fill_kernel<<<(N_EDGES + 255) / 256, 256, 0, stream>>>(srcv, dstv, ew, cur, ewp);

    // ---- Layer 1 ----
    gemm1_kernel<<<(N_NODES + 63) / 64, 256, 0, stream>>>(x, W1, A);
    {
        unsigned total = (unsigned)N_NODES * 24;
        gather_agg_kernel<96><<<(total + 255) / 256, 256, 0, stream>>>(A, off, ewp, b1, B);
    }

    // ---- Layer 2 ----
    gemm2_kernel<<<(N_NODES + 63) / 64, 256, 0, stream>>>(B, W2, A);
    {
        unsigned total = (unsigned)N_NODES * 16;
        gather_agg_kernel<64><<<(total + 255) / 256, 256, 0, stream>>>(A, off, ewp, b2, B);
    }

    // ---- Pool + head ----
    colsum_kernel<<<(N_NODES + 255) / 256, 256, 0, stream>>>(B, pooled);
    final_kernel<<<1, 64, 0, stream>>>(pooled, sub_fea, fc_w, fc_b, out);
}

// Round 6
// 224.732 us; speedup vs baseline: 1.4181x; 1.1525x over previous
//
#include <hip/hip_runtime.h>
#include <hip/hip_bf16.h>

#define N_NODES 50000
#define N_EDGES 800000
#define SCAN_NBLK ((N_NODES + 255) / 256)   // 196

typedef __attribute__((ext_vector_type(8))) short short8;
typedef __attribute__((ext_vector_type(4))) float float4v;

__device__ __forceinline__ unsigned short f2bf(float f) {
    unsigned u = __float_as_uint(f);
    u += 0x7FFF + ((u >> 16) & 1);          // round-to-nearest-even
    return (unsigned short)(u >> 16);
}

// ---------------------------------------------------------------------------
// Weight prep: Wt1[96][256] = bf16(W1[k][n]); Wt2[64][96] = bf16(W2[k][n])
// ---------------------------------------------------------------------------
__global__ __launch_bounds__(256) void convw_kernel(const float* __restrict__ W1,
                                                    const float* __restrict__ W2,
                                                    unsigned short* __restrict__ Wt1,
                                                    unsigned short* __restrict__ Wt2) {
    int i = blockIdx.x * 256 + threadIdx.x;
    if (i < 96 * 256) {
        int n = i >> 8, k = i & 255;
        Wt1[i] = f2bf(W1[k * 96 + n]);
    } else {
        int j = i - 96 * 256;
        if (j < 64 * 96) {
            int n = j / 96, k = j - n * 96;
            Wt2[j] = f2bf(W2[k * 64 + n]);
        }
    }
}

// ---------------------------------------------------------------------------
// MFMA GEMM: out[rows][N] = f32(src[rows][K]) @ bf16(Wt[N][K])^T
// BM=64 (4 waves x 16 rows), BK=32, mfma_f32_16x16x32_bf16.
// A/B frag layout: elem i of lane l -> k=(l>>4)*8+i, row/col=l&15.
// C/D: col=lane&15, row=(lane>>4)*4+reg.
// ---------------------------------------------------------------------------
template <int K, int N>
__global__ __launch_bounds__(256) void gemm_mfma_kernel(const float* __restrict__ src,
                                                        const unsigned short* __restrict__ Wt,
                                                        float* __restrict__ out) {
    constexpr int NF = N / 16;          // n-frags
    constexpr int LDA = 40;             // 32 k + 8 pad (80B rows, 16B aligned)
    __shared__ unsigned short a_lds[64 * LDA];
    __shared__ unsigned short b_lds[N * LDA];
    const int tid = threadIdx.x;
    const int lane = tid & 63;
    const int w = tid >> 6;             // wave 0..3
    const int row0 = blockIdx.x * 64;
    const int fr = lane & 15;
    const int fk = (lane >> 4) * 8;

    float4v acc[NF];
    #pragma unroll
    for (int nn = 0; nn < NF; ++nn) acc[nn] = (float4v){0.f, 0.f, 0.f, 0.f};

    const int srow = tid >> 2;          // staging row 0..63
    const int sko  = (tid & 3) * 8;     // staging k-octet

    for (int k0 = 0; k0 < K; k0 += 32) {
        // stage A: 64x32 f32 -> bf16 (one short8 per thread)
        {
            int grow = row0 + srow;
            float f[8];
            #pragma unroll
            for (int i = 0; i < 8; ++i) f[i] = 0.f;
            if (grow < N_NODES) {
                const float4* p = reinterpret_cast<const float4*>(&src[(size_t)grow * K + k0 + sko]);
                float4 v0 = p[0], v1 = p[1];
                f[0] = v0.x; f[1] = v0.y; f[2] = v0.z; f[3] = v0.w;
                f[4] = v1.x; f[5] = v1.y; f[6] = v1.z; f[7] = v1.w;
            }
            short8 s;
            #pragma unroll
            for (int i = 0; i < 8; ++i) s[i] = (short)f2bf(f[i]);
            *reinterpret_cast<short8*>(&a_lds[srow * LDA + sko]) = s;
        }
        // stage B: Nx32 bf16 contiguous copy
        for (int c = tid; c < N * 4; c += 256) {
            int n = c >> 2, ko = (c & 3) * 8;
            short8 s = *reinterpret_cast<const short8*>(&Wt[(size_t)n * K + k0 + ko]);
            *reinterpret_cast<short8*>(&b_lds[n * LDA + ko]) = s;
        }
        __syncthreads();
        short8 af = *reinterpret_cast<short8*>(&a_lds[(w * 16 + fr) * LDA + fk]);
        #pragma unroll
        for (int nn = 0; nn < NF; ++nn) {
            short8 bf = *reinterpret_cast<short8*>(&b_lds[(nn * 16 + fr) * LDA + fk]);
            acc[nn] = __builtin_amdgcn_mfma_f32_16x16x32_bf16(af, bf, acc[nn], 0, 0, 0);
        }
        __syncthreads();
    }
    // epilogue
    const int orow_base = row0 + w * 16 + (lane >> 4) * 4;
    const int ocol = lane & 15;
    #pragma unroll
    for (int nn = 0; nn < NF; ++nn) {
        #pragma unroll
        for (int r = 0; r < 4; ++r) {
            int grow = orow_base + r;
            if (grow < N_NODES) out[(size_t)grow * N + nn * 16 + ocol] = acc[nn][r];
        }
    }
}

// ---------------------------------------------------------------------------
// CSR build step 1: histogram of dst
// ---------------------------------------------------------------------------
__global__ __launch_bounds__(256) void hist_kernel(const int* __restrict__ dstv,
                                                   int* __restrict__ cnt) {
    int e = blockIdx.x * 256 + threadIdx.x;
    if (e < N_EDGES) atomicAdd(&cnt[dstv[e]], 1);
}

// ---------------------------------------------------------------------------
// Multi-block exclusive scan of cnt[50000] -> off[50001] (+ cursor copy).
// ---------------------------------------------------------------------------
__global__ __launch_bounds__(256) void scan1_kernel(const int* __restrict__ cnt,
                                                    int* __restrict__ bsum) {
    __shared__ int red[256];
    const int t = threadIdx.x;
    const int i = blockIdx.x * 256 + t;
    red[t] = (i < N_NODES) ? cnt[i] : 0;
    __syncthreads();
    #pragma unroll
    for (int d = 128; d > 0; d >>= 1) {
        if (t < d) red[t] += red[t + d];
        __syncthreads();
    }
    if (t == 0) bsum[blockIdx.x] = red[0];
}

__global__ __launch_bounds__(256) void scan2_kernel(int* __restrict__ bsum) {
    __shared__ int sh[256];
    const int t = threadIdx.x;
    int v = (t < SCAN_NBLK) ? bsum[t] : 0;
    sh[t] = v;
    __syncthreads();
    #pragma unroll
    for (int d = 1; d < 256; d <<= 1) {
        int u = (t >= d) ? sh[t - d] : 0;
        __syncthreads();
        sh[t] += u;
        __syncthreads();
    }
    if (t < SCAN_NBLK) bsum[t] = sh[t] - v;
}

__global__ __launch_bounds__(256) void scan3_kernel(const int* __restrict__ cnt,
                                                    const int* __restrict__ bsum,
                                                    int* __restrict__ off,
                                                    int* __restrict__ cur) {
    __shared__ int sh[256];
    const int t = threadIdx.x;
    const int i = blockIdx.x * 256 + t;
    int v = (i < N_NODES) ? cnt[i] : 0;
    sh[t] = v;
    __syncthreads();
    #pragma unroll
    for (int d = 1; d < 256; d <<= 1) {
        int u = (t >= d) ? sh[t - d] : 0;
        __syncthreads();
        sh[t] += u;
        __syncthreads();
    }
    int excl = sh[t] - v + bsum[blockIdx.x];
    if (i < N_NODES) {
        off[i] = excl;
        cur[i] = excl;
    }
    if (i == N_NODES - 1) off[N_NODES] = excl + v;
}

// ---------------------------------------------------------------------------
// CSR build step 3: fill packed (src, weight_bits) per edge, grouped by dst.
// ---------------------------------------------------------------------------
__global__ __launch_bounds__(256) void fill_kernel(const int* __restrict__ srcv,
                                                   const int* __restrict__ dstv,
                                                   const float* __restrict__ wv,
                                                   int* __restrict__ cur,
                                                   int2* __restrict__ ewp) {
    int e = blockIdx.x * 256 + threadIdx.x;
    if (e >= N_EDGES) return;
    int d = dstv[e];
    int pos = atomicAdd(&cur[d], 1);
    ewp[pos] = make_int2(srcv[e], __float_as_int(wv[e]));
}

// ---------------------------------------------------------------------------
// Gather aggregation, 4x-unrolled for MLP:
// out[n][:] = relu( sum_{e in row n} sup[src_e]*w_e + b )
// ---------------------------------------------------------------------------
template <int DIM>
__global__ __launch_bounds__(256) void gather_agg_kernel(const float* __restrict__ sup,
                                                         const int* __restrict__ off,
                                                         const int2* __restrict__ ewp,
                                                         const float* __restrict__ bias,
                                                         float* __restrict__ outp) {
    const int NQ = DIM / 4;
    unsigned gid = blockIdx.x * 256u + threadIdx.x;
    if (gid >= (unsigned)N_NODES * NQ) return;
    unsigned n = gid / NQ;
    unsigned q = gid - n * NQ;
    const int e0 = off[n], e1 = off[n + 1];
    float4 a0 = make_float4(0.f, 0.f, 0.f, 0.f);
    float4 a1 = make_float4(0.f, 0.f, 0.f, 0.f);
    float4 a2 = make_float4(0.f, 0.f, 0.f, 0.f);
    float4 a3 = make_float4(0.f, 0.f, 0.f, 0.f);
    int e = e0;
    for (; e + 4 <= e1; e += 4) {
        int2 p0 = ewp[e];
        int2 p1 = ewp[e + 1];
        int2 p2 = ewp[e + 2];
        int2 p3 = ewp[e + 3];
        float4 v0 = *reinterpret_cast<const float4*>(&sup[(size_t)p0.x * DIM + q * 4]);
        float4 v1 = *reinterpret_cast<const float4*>(&sup[(size_t)p1.x * DIM + q * 4]);
        float4 v2 = *reinterpret_cast<const float4*>(&sup[(size_t)p2.x * DIM + q * 4]);
        float4 v3 = *reinterpret_cast<const float4*>(&sup[(size_t)p3.x * DIM + q * 4]);
        float w0 = __int_as_float(p0.y);
        float w1 = __int_as_float(p1.y);
        float w2 = __int_as_float(p2.y);
        float w3 = __int_as_float(p3.y);
        a0.x += v0.x * w0; a0.y += v0.y * w0; a0.z += v0.z * w0; a0.w += v0.w * w0;
        a1.x += v1.x * w1; a1.y += v1.y * w1; a1.z += v1.z * w1; a1.w += v1.w * w1;
        a2.x += v2.x * w2; a2.y += v2.y * w2; a2.z += v2.z * w2; a2.w += v2.w * w2;
        a3.x += v3.x * w3; a3.y += v3.y * w3; a3.z += v3.z * w3; a3.w += v3.w * w3;
    }
    for (; e < e1; ++e) {
        int2 p = ewp[e];
        float w = __int_as_float(p.y);
        float4 v = *reinterpret_cast<const float4*>(&sup[(size_t)p.x * DIM + q * 4]);
        a0.x += v.x * w; a0.y += v.y * w; a0.z += v.z * w; a0.w += v.w * w;
    }
    a0.x += a1.x + a2.x + a3.x;
    a0.y += a1.y + a2.y + a3.y;
    a0.z += a1.z + a2.z + a3.z;
    a0.w += a1.w + a2.w + a3.w;
    const float4 bb = *reinterpret_cast<const float4*>(&bias[q * 4]);
    a0.x = fmaxf(a0.x + bb.x, 0.f);
    a0.y = fmaxf(a0.y + bb.y, 0.f);
    a0.z = fmaxf(a0.z + bb.z, 0.f);
    a0.w = fmaxf(a0.w + bb.w, 0.f);
    *reinterpret_cast<float4*>(&outp[(size_t)n * DIM + q * 4]) = a0;
}

// ---------------------------------------------------------------------------
// Column-sum of h2 (already bias+relu'd) over all nodes -> pooled[64]
// ---------------------------------------------------------------------------
__global__ __launch_bounds__(256) void colsum_kernel(const float* __restrict__ h2,
                                                     float* __restrict__ pooled) {
    __shared__ float red[4][64];
    const int t = threadIdx.x;
    const int c = t & 63, r = t >> 6;
    float s = 0.f;
    const int base = blockIdx.x * 256;
    for (int i = r; i < 256; i += 4) {
        int n = base + i;
        if (n < N_NODES) s += h2[(size_t)n * 64 + c];
    }
    red[r][c] = s;
    __syncthreads();
    if (r == 0) {
        float v = red[0][c] + red[1][c] + red[2][c] + red[3][c];
        unsafeAtomicAdd(&pooled[c], v);
    }
}

// ---------------------------------------------------------------------------
// Final head: selu(pooled/N) + 0.5*(sub_fea @ fc_w^T + fc_b) -> log_softmax
// ---------------------------------------------------------------------------
__global__ void final_kernel(const float* __restrict__ pooled,
                             const float* __restrict__ sub_fea,
                             const float* __restrict__ fc_w,
                             const float* __restrict__ fc_b,
                             float* __restrict__ out) {
    const int c = threadIdx.x;  // 0..63
    float p = pooled[c] * (1.0f / (float)N_NODES);
    const float kScale = 1.0507009873554805f;
    const float kAlpha = 1.6732632423543772f;
    float se = (p > 0.f) ? kScale * p : kScale * kAlpha * (expf(p) - 1.f);
    float xe = fc_b[c];
    for (int k = 0; k < 128; ++k) xe += sub_fea[k] * fc_w[c * 128 + k];
    float v = se + 0.5f * xe;
    float m = v;
    #pragma unroll
    for (int off = 32; off >= 1; off >>= 1) m = fmaxf(m, __shfl_xor(m, off));
    float ex = expf(v - m);
    float ss = ex;
    #pragma unroll
    for (int off = 32; off >= 1; off >>= 1) ss += __shfl_xor(ss, off);
    out[c] = v - m - logf(ss);
}

// ---------------------------------------------------------------------------
extern "C" void kernel_launch(void* const* d_in, const int* in_sizes, int n_in,
                              void* d_out, int out_size, void* d_ws, size_t ws_size,
                              hipStream_t stream) {
    const float* x       = (const float*)d_in[0];
    const int*   ei      = (const int*)d_in[1];   // [2][E]: src row 0, dst row 1
    const float* ew      = (const float*)d_in[2];
    const float* sub_fea = (const float*)d_in[3];
    const float* W1      = (const float*)d_in[4];
    const float* b1      = (const float*)d_in[5];
    const float* W2      = (const float*)d_in[6];
    const float* b2      = (const float*)d_in[7];
    const float* fc_w    = (const float*)d_in[8];
    const float* fc_b    = (const float*)d_in[9];
    float* out = (float*)d_out;

    // Workspace layout (bytes). A reused: support1 then support2. B: h1 then h2.
    char* base = (char*)d_ws;
    float* A      = (float*)(base);                       // 4.8M floats (19.2 MB)
    float* B      = (float*)(base + 19200000);            // 4.8M floats (19.2 MB)
    float* pooled = (float*)(base + 38400000);            // 64 floats
    int*   off    = (int*)  (base + 38400512);            // 50001 ints
    int*   cnt    = (int*)  (base + 38600960);            // 50000 ints
    int*   cur    = (int*)  (base + 38801408);            // 50000 ints
    int*   bsum   = (int*)  (base + 39001856);            // 256 ints
    int2*  ewp    = (int2*) (base + 39002880);            // 800000 int2 (6.4 MB)
    unsigned short* Wt1 = (unsigned short*)(base + 45402880);  // 96*256 bf16
    unsigned short* Wt2 = (unsigned short*)(base + 45452032);  // 64*96 bf16

    const int* srcv = ei;
    const int* dstv = ei + N_EDGES;

    // ---- prep: weights -> bf16 transposed ----
    convw_kernel<<<(96 * 256 + 64 * 96 + 255) / 256, 256, 0, stream>>>(W1, W2, Wt1, Wt2);

    // ---- CSR build (shared by both layers) ----
    hipMemsetAsync(cnt, 0, N_NODES * 4, stream);
    hipMemsetAsync(pooled, 0, 64 * 4, stream);
    hist_kernel<<<(N_EDGES + 255) / 256, 256, 0, stream>>>(dstv, cnt);
    scan1_kernel<<<SCAN_NBLK, 256, 0, stream>>>(cnt, bsum);
    scan2_kernel<<<1, 256, 0, stream>>>(bsum);
    scan3_kernel<<<SCAN_NBLK, 256, 0, stream>>>(cnt, bsum, off, cur);
    fill_kernel<<<(N_EDGES + 255) / 256, 256, 0, stream>>>(srcv, dstv, ew, cur, ewp);

    // ---- Layer 1 ----
    gemm_mfma_kernel<256, 96><<<(N_NODES + 63) / 64, 256, 0, stream>>>(x, Wt1, A);
    {
        unsigned total = (unsigned)N_NODES * 24;
        gather_agg_kernel<96><<<(total + 255) / 256, 256, 0, stream>>>(A, off, ewp, b1, B);
    }

    // ---- Layer 2 ----
    gemm_mfma_kernel<96, 64><<<(N_NODES + 63) / 64, 256, 0, stream>>>(B, Wt2, A);
    {
        unsigned total = (unsigned)N_NODES * 16;
        gather_agg_kernel<64><<<(total + 255) / 256, 256, 0, stream>>>(A, off, ewp, b2, B);
    }

    // ---- Pool + head ----
    colsum_kernel<<<(N_NODES + 255) / 256, 256, 0, stream>>>(B, pooled);
    final_kernel<<<1, 64, 0, stream>>>(pooled, sub_fea, fc_w, fc_b, out);
}

// Round 7
// 206.149 us; speedup vs baseline: 1.5459x; 1.0901x over previous
//
#include <hip/hip_runtime.h>
#include <hip/hip_bf16.h>

#define N_NODES 50000
#define N_EDGES 800000
#define SCAN_NBLK ((N_NODES + 255) / 256)   // 196

typedef __attribute__((ext_vector_type(8))) short short8;
typedef __attribute__((ext_vector_type(4))) float float4v;

__device__ __forceinline__ unsigned short f2bf(float f) {
    unsigned u = __float_as_uint(f);
    u += 0x7FFF + ((u >> 16) & 1);          // round-to-nearest-even
    return (unsigned short)(u >> 16);
}
__device__ __forceinline__ float bf2f(unsigned short u) {
    return __uint_as_float((unsigned)u << 16);
}

// ---------------------------------------------------------------------------
// Weight prep: Wt1[96][256] = bf16(W1[k][n]); Wt2[64][96] = bf16(W2[k][n])
// ---------------------------------------------------------------------------
__global__ __launch_bounds__(256) void convw_kernel(const float* __restrict__ W1,
                                                    const float* __restrict__ W2,
                                                    unsigned short* __restrict__ Wt1,
                                                    unsigned short* __restrict__ Wt2) {
    int i = blockIdx.x * 256 + threadIdx.x;
    if (i < 96 * 256) {
        int n = i >> 8, k = i & 255;
        Wt1[i] = f2bf(W1[k * 96 + n]);
    } else {
        int j = i - 96 * 256;
        if (j < 64 * 96) {
            int n = j / 96, k = j - n * 96;
            Wt2[j] = f2bf(W2[k * 64 + n]);
        }
    }
}

// ---------------------------------------------------------------------------
// MFMA GEMM: outb[rows][N](bf16) = src[rows][K] @ Wt[N][K]^T
// src is f32 (IN_BF16=false, cvt during staging) or bf16 (straight copy).
// BM=64 (4 waves x 16 rows), BK=32, mfma_f32_16x16x32_bf16.
// A/B frag: elem i of lane l -> k=(l>>4)*8+i, row/col=l&15.
// C/D: col=lane&15, row=(lane>>4)*4+reg.
// ---------------------------------------------------------------------------
template <int K, int N, bool IN_BF16>
__global__ __launch_bounds__(256) void gemm_mfma_kernel(const void* __restrict__ src_,
                                                        const unsigned short* __restrict__ Wt,
                                                        unsigned short* __restrict__ outb) {
    constexpr int NF = N / 16;          // n-frags
    constexpr int LDA = 40;             // 32 k + 8 pad (80B rows, 16B aligned)
    __shared__ unsigned short a_lds[64 * LDA];
    __shared__ unsigned short b_lds[N * LDA];
    const int tid = threadIdx.x;
    const int lane = tid & 63;
    const int w = tid >> 6;             // wave 0..3
    const int row0 = blockIdx.x * 64;
    const int fr = lane & 15;
    const int fk = (lane >> 4) * 8;

    float4v acc[NF];
    #pragma unroll
    for (int nn = 0; nn < NF; ++nn) acc[nn] = (float4v){0.f, 0.f, 0.f, 0.f};

    const int srow = tid >> 2;          // staging row 0..63
    const int sko  = (tid & 3) * 8;     // staging k-octet

    for (int k0 = 0; k0 < K; k0 += 32) {
        // stage A: 64x32 -> bf16 LDS
        {
            int grow = row0 + srow;
            short8 s = (short8){0, 0, 0, 0, 0, 0, 0, 0};
            if (grow < N_NODES) {
                if constexpr (IN_BF16) {
                    const unsigned short* src = (const unsigned short*)src_;
                    s = *reinterpret_cast<const short8*>(&src[(size_t)grow * K + k0 + sko]);
                } else {
                    const float* src = (const float*)src_;
                    const float4* p = reinterpret_cast<const float4*>(&src[(size_t)grow * K + k0 + sko]);
                    float4 v0 = p[0], v1 = p[1];
                    s[0] = (short)f2bf(v0.x); s[1] = (short)f2bf(v0.y);
                    s[2] = (short)f2bf(v0.z); s[3] = (short)f2bf(v0.w);
                    s[4] = (short)f2bf(v1.x); s[5] = (short)f2bf(v1.y);
                    s[6] = (short)f2bf(v1.z); s[7] = (short)f2bf(v1.w);
                }
            }
            *reinterpret_cast<short8*>(&a_lds[srow * LDA + sko]) = s;
        }
        // stage B: Nx32 bf16 contiguous copy
        for (int c = tid; c < N * 4; c += 256) {
            int n = c >> 2, ko = (c & 3) * 8;
            short8 s = *reinterpret_cast<const short8*>(&Wt[(size_t)n * K + k0 + ko]);
            *reinterpret_cast<short8*>(&b_lds[n * LDA + ko]) = s;
        }
        __syncthreads();
        short8 af = *reinterpret_cast<short8*>(&a_lds[(w * 16 + fr) * LDA + fk]);
        #pragma unroll
        for (int nn = 0; nn < NF; ++nn) {
            short8 bf = *reinterpret_cast<short8*>(&b_lds[(nn * 16 + fr) * LDA + fk]);
            acc[nn] = __builtin_amdgcn_mfma_f32_16x16x32_bf16(af, bf, acc[nn], 0, 0, 0);
        }
        __syncthreads();
    }
    // epilogue: bf16 store
    const int orow_base = row0 + w * 16 + (lane >> 4) * 4;
    const int ocol = lane & 15;
    #pragma unroll
    for (int nn = 0; nn < NF; ++nn) {
        #pragma unroll
        for (int r = 0; r < 4; ++r) {
            int grow = orow_base + r;
            if (grow < N_NODES) outb[(size_t)grow * N + nn * 16 + ocol] = f2bf(acc[nn][r]);
        }
    }
}

// ---------------------------------------------------------------------------
// CSR build step 1: histogram of dst
// ---------------------------------------------------------------------------
__global__ __launch_bounds__(256) void hist_kernel(const int* __restrict__ dstv,
                                                   int* __restrict__ cnt) {
    int e = blockIdx.x * 256 + threadIdx.x;
    if (e < N_EDGES) atomicAdd(&cnt[dstv[e]], 1);
}

// ---------------------------------------------------------------------------
// Multi-block exclusive scan of cnt[50000] -> off[50001] (+ cursor copy).
// ---------------------------------------------------------------------------
__global__ __launch_bounds__(256) void scan1_kernel(const int* __restrict__ cnt,
                                                    int* __restrict__ bsum) {
    __shared__ int red[256];
    const int t = threadIdx.x;
    const int i = blockIdx.x * 256 + t;
    red[t] = (i < N_NODES) ? cnt[i] : 0;
    __syncthreads();
    #pragma unroll
    for (int d = 128; d > 0; d >>= 1) {
        if (t < d) red[t] += red[t + d];
        __syncthreads();
    }
    if (t == 0) bsum[blockIdx.x] = red[0];
}

__global__ __launch_bounds__(256) void scan2_kernel(int* __restrict__ bsum) {
    __shared__ int sh[256];
    const int t = threadIdx.x;
    int v = (t < SCAN_NBLK) ? bsum[t] : 0;
    sh[t] = v;
    __syncthreads();
    #pragma unroll
    for (int d = 1; d < 256; d <<= 1) {
        int u = (t >= d) ? sh[t - d] : 0;
        __syncthreads();
        sh[t] += u;
        __syncthreads();
    }
    if (t < SCAN_NBLK) bsum[t] = sh[t] - v;
}

__global__ __launch_bounds__(256) void scan3_kernel(const int* __restrict__ cnt,
                                                    const int* __restrict__ bsum,
                                                    int* __restrict__ off,
                                                    int* __restrict__ cur) {
    __shared__ int sh[256];
    const int t = threadIdx.x;
    const int i = blockIdx.x * 256 + t;
    int v = (i < N_NODES) ? cnt[i] : 0;
    sh[t] = v;
    __syncthreads();
    #pragma unroll
    for (int d = 1; d < 256; d <<= 1) {
        int u = (t >= d) ? sh[t - d] : 0;
        __syncthreads();
        sh[t] += u;
        __syncthreads();
    }
    int excl = sh[t] - v + bsum[blockIdx.x];
    if (i < N_NODES) {
        off[i] = excl;
        cur[i] = excl;
    }
    if (i == N_NODES - 1) off[N_NODES] = excl + v;
}

// ---------------------------------------------------------------------------
// CSR build step 3: fill packed edge word (src<<15 | w15), grouped by dst.
// ---------------------------------------------------------------------------
__global__ __launch_bounds__(256) void fill_kernel(const int* __restrict__ srcv,
                                                   const int* __restrict__ dstv,
                                                   const float* __restrict__ wv,
                                                   int* __restrict__ cur,
                                                   unsigned* __restrict__ ewq) {
    int e = blockIdx.x * 256 + threadIdx.x;
    if (e >= N_EDGES) return;
    int d = dstv[e];
    unsigned w15 = __float2uint_rn(wv[e] * 32768.0f);
    if (w15 > 32767u) w15 = 32767u;
    unsigned packed = ((unsigned)srcv[e] << 15) | w15;
    int pos = atomicAdd(&cur[d], 1);
    ewq[pos] = packed;
}

// ---------------------------------------------------------------------------
// Gather aggregation (bf16 support table, packed 4B edges), 4x-unrolled:
// out[n][:] = relu( sum_{e in row n} sup[src_e]*w_e + b )
// One thread per (node, channel-quad).
// ---------------------------------------------------------------------------
template <int DIM, bool OUT_BF16>
__global__ __launch_bounds__(256) void gather_agg_kernel(const unsigned short* __restrict__ supb,
                                                         const int* __restrict__ off,
                                                         const unsigned* __restrict__ ewq,
                                                         const float* __restrict__ bias,
                                                         void* __restrict__ outp) {
    const int NQ = DIM / 4;
    const float kInv = 1.0f / 32768.0f;
    unsigned gid = blockIdx.x * 256u + threadIdx.x;
    if (gid >= (unsigned)N_NODES * NQ) return;
    unsigned n = gid / NQ;
    unsigned q = gid - n * NQ;
    const int e0 = off[n], e1 = off[n + 1];
    float4 a0 = make_float4(0.f, 0.f, 0.f, 0.f);
    float4 a1 = make_float4(0.f, 0.f, 0.f, 0.f);
    float4 a2 = make_float4(0.f, 0.f, 0.f, 0.f);
    float4 a3 = make_float4(0.f, 0.f, 0.f, 0.f);
    int e = e0;
    for (; e + 4 <= e1; e += 4) {
        unsigned p0 = ewq[e];
        unsigned p1 = ewq[e + 1];
        unsigned p2 = ewq[e + 2];
        unsigned p3 = ewq[e + 3];
        ushort4 u0 = *reinterpret_cast<const ushort4*>(&supb[(size_t)(p0 >> 15) * DIM + q * 4]);
        ushort4 u1 = *reinterpret_cast<const ushort4*>(&supb[(size_t)(p1 >> 15) * DIM + q * 4]);
        ushort4 u2 = *reinterpret_cast<const ushort4*>(&supb[(size_t)(p2 >> 15) * DIM + q * 4]);
        ushort4 u3 = *reinterpret_cast<const ushort4*>(&supb[(size_t)(p3 >> 15) * DIM + q * 4]);
        float w0 = (float)(p0 & 32767u) * kInv;
        float w1 = (float)(p1 & 32767u) * kInv;
        float w2 = (float)(p2 & 32767u) * kInv;
        float w3 = (float)(p3 & 32767u) * kInv;
        a0.x += bf2f(u0.x) * w0; a0.y += bf2f(u0.y) * w0;
        a0.z += bf2f(u0.z) * w0; a0.w += bf2f(u0.w) * w0;
        a1.x += bf2f(u1.x) * w1; a1.y += bf2f(u1.y) * w1;
        a1.z += bf2f(u1.z) * w1; a1.w += bf2f(u1.w) * w1;
        a2.x += bf2f(u2.x) * w2; a2.y += bf2f(u2.y) * w2;
        a2.z += bf2f(u2.z) * w2; a2.w += bf2f(u2.w) * w2;
        a3.x += bf2f(u3.x) * w3; a3.y += bf2f(u3.y) * w3;
        a3.z += bf2f(u3.z) * w3; a3.w += bf2f(u3.w) * w3;
    }
    for (; e < e1; ++e) {
        unsigned p = ewq[e];
        float w = (float)(p & 32767u) * kInv;
        ushort4 u = *reinterpret_cast<const ushort4*>(&supb[(size_t)(p >> 15) * DIM + q * 4]);
        a0.x += bf2f(u.x) * w; a0.y += bf2f(u.y) * w;
        a0.z += bf2f(u.z) * w; a0.w += bf2f(u.w) * w;
    }
    a0.x += a1.x + a2.x + a3.x;
    a0.y += a1.y + a2.y + a3.y;
    a0.z += a1.z + a2.z + a3.z;
    a0.w += a1.w + a2.w + a3.w;
    const float4 bb = *reinterpret_cast<const float4*>(&bias[q * 4]);
    a0.x = fmaxf(a0.x + bb.x, 0.f);
    a0.y = fmaxf(a0.y + bb.y, 0.f);
    a0.z = fmaxf(a0.z + bb.z, 0.f);
    a0.w = fmaxf(a0.w + bb.w, 0.f);
    if (OUT_BF16) {
        ushort4 o;
        o.x = f2bf(a0.x); o.y = f2bf(a0.y); o.z = f2bf(a0.z); o.w = f2bf(a0.w);
        *reinterpret_cast<ushort4*>(&((unsigned short*)outp)[(size_t)n * DIM + q * 4]) = o;
    } else {
        *reinterpret_cast<float4*>(&((float*)outp)[(size_t)n * DIM + q * 4]) = a0;
    }
}

// ---------------------------------------------------------------------------
// Column-sum of h2 (f32, already bias+relu'd) over all nodes -> pooled[64]
// ---------------------------------------------------------------------------
__global__ __launch_bounds__(256) void colsum_kernel(const float* __restrict__ h2,
                                                     float* __restrict__ pooled) {
    __shared__ float red[4][64];
    const int t = threadIdx.x;
    const int c = t & 63, r = t >> 6;
    float s = 0.f;
    const int base = blockIdx.x * 256;
    for (int i = r; i < 256; i += 4) {
        int n = base + i;
        if (n < N_NODES) s += h2[(size_t)n * 64 + c];
    }
    red[r][c] = s;
    __syncthreads();
    if (r == 0) {
        float v = red[0][c] + red[1][c] + red[2][c] + red[3][c];
        unsafeAtomicAdd(&pooled[c], v);
    }
}

// ---------------------------------------------------------------------------
// Final head: selu(pooled/N) + 0.5*(sub_fea @ fc_w^T + fc_b) -> log_softmax
// ---------------------------------------------------------------------------
__global__ void final_kernel(const float* __restrict__ pooled,
                             const float* __restrict__ sub_fea,
                             const float* __restrict__ fc_w,
                             const float* __restrict__ fc_b,
                             float* __restrict__ out) {
    const int c = threadIdx.x;  // 0..63
    float p = pooled[c] * (1.0f / (float)N_NODES);
    const float kScale = 1.0507009873554805f;
    const float kAlpha = 1.6732632423543772f;
    float se = (p > 0.f) ? kScale * p : kScale * kAlpha * (expf(p) - 1.f);
    float xe = fc_b[c];
    for (int k = 0; k < 128; ++k) xe += sub_fea[k] * fc_w[c * 128 + k];
    float v = se + 0.5f * xe;
    float m = v;
    #pragma unroll
    for (int off = 32; off >= 1; off >>= 1) m = fmaxf(m, __shfl_xor(m, off));
    float ex = expf(v - m);
    float ss = ex;
    #pragma unroll
    for (int off = 32; off >= 1; off >>= 1) ss += __shfl_xor(ss, off);
    out[c] = v - m - logf(ss);
}

// ---------------------------------------------------------------------------
extern "C" void kernel_launch(void* const* d_in, const int* in_sizes, int n_in,
                              void* d_out, int out_size, void* d_ws, size_t ws_size,
                              hipStream_t stream) {
    const float* x       = (const float*)d_in[0];
    const int*   ei      = (const int*)d_in[1];   // [2][E]: src row 0, dst row 1
    const float* ew      = (const float*)d_in[2];
    const float* sub_fea = (const float*)d_in[3];
    const float* W1      = (const float*)d_in[4];
    const float* b1      = (const float*)d_in[5];
    const float* W2      = (const float*)d_in[6];
    const float* b2      = (const float*)d_in[7];
    const float* fc_w    = (const float*)d_in[8];
    const float* fc_b    = (const float*)d_in[9];
    float* out = (float*)d_out;

    // Workspace layout (bytes).
    // A (bf16): support1 [50000][96] (9.6MB), then support2 [50000][64] (6.4MB)
    // B: h1 bf16 [50000][96] (9.6MB), then h2 f32 [50000][64] (12.8MB)
    char* base = (char*)d_ws;
    unsigned short* A   = (unsigned short*)(base);              // 9.6 MB
    char*  Bb    = base + 9600000;                              // 12.8 MB region
    float* pooled = (float*)(base + 22400000);                  // 64 floats
    int*   off   = (int*)(base + 22400512);                     // 50001 ints
    int*   cnt   = (int*)(base + 22601216);                     // 50000 ints
    int*   cur   = (int*)(base + 22801920);                     // 50000 ints
    int*   bsum  = (int*)(base + 23002624);                     // 256 ints
    unsigned* ewq = (unsigned*)(base + 23003648);               // 800000 u32 (3.2 MB)
    unsigned short* Wt1 = (unsigned short*)(base + 26203648);   // 96*256 bf16
    unsigned short* Wt2 = (unsigned short*)(base + 26252800);   // 64*96 bf16

    const int* srcv = ei;
    const int* dstv = ei + N_EDGES;

    // ---- prep: weights -> bf16 transposed ----
    convw_kernel<<<(96 * 256 + 64 * 96 + 255) / 256, 256, 0, stream>>>(W1, W2, Wt1, Wt2);

    // ---- CSR build (shared by both layers) ----
    hipMemsetAsync(cnt, 0, N_NODES * 4, stream);
    hipMemsetAsync(pooled, 0, 64 * 4, stream);
    hist_kernel<<<(N_EDGES + 255) / 256, 256, 0, stream>>>(dstv, cnt);
    scan1_kernel<<<SCAN_NBLK, 256, 0, stream>>>(cnt, bsum);
    scan2_kernel<<<1, 256, 0, stream>>>(bsum);
    scan3_kernel<<<SCAN_NBLK, 256, 0, stream>>>(cnt, bsum, off, cur);
    fill_kernel<<<(N_EDGES + 255) / 256, 256, 0, stream>>>(srcv, dstv, ew, cur, ewq);

    // ---- Layer 1: support1 = bf16(x @ W1); h1 = bf16(relu(agg + b1)) ----
    gemm_mfma_kernel<256, 96, false><<<(N_NODES + 63) / 64, 256, 0, stream>>>(x, Wt1, A);
    {
        unsigned total = (unsigned)N_NODES * 24;
        gather_agg_kernel<96, true><<<(total + 255) / 256, 256, 0, stream>>>(
            A, off, ewq, b1, Bb);
    }

    // ---- Layer 2: support2 = bf16(h1 @ W2); h2 = f32 relu(agg + b2) ----
    gemm_mfma_kernel<96, 64, true><<<(N_NODES + 63) / 64, 256, 0, stream>>>(Bb, Wt2, A);
    {
        unsigned total = (unsigned)N_NODES * 16;
        gather_agg_kernel<64, false><<<(total + 255) / 256, 256, 0, stream>>>(
            A, off, ewq, b2, Bb);
    }

    // ---- Pool + head ----
    colsum_kernel<<<(N_NODES + 255) / 256, 256, 0, stream>>>((const float*)Bb, pooled);
    final_kernel<<<1, 64, 0, stream>>>(pooled, sub_fea, fc_w, fc_b, out);
}

// Round 8
// 178.203 us; speedup vs baseline: 1.7883x; 1.1568x over previous
//
#include <hip/hip_runtime.h>
#include <hip/hip_bf16.h>

#define N_NODES 50000
#define N_EDGES 800000
#define SCAN_NBLK ((N_NODES + 255) / 256)   // 196
#define NBKT ((N_NODES + 127) / 128)        // 391 coarse buckets (128 dst each)

typedef __attribute__((ext_vector_type(8))) short short8;
typedef __attribute__((ext_vector_type(4))) float float4v;

__device__ __forceinline__ unsigned short f2bf(float f) {
    unsigned u = __float_as_uint(f);
    u += 0x7FFF + ((u >> 16) & 1);          // round-to-nearest-even
    return (unsigned short)(u >> 16);
}
__device__ __forceinline__ float bf2f(unsigned short u) {
    return __uint_as_float((unsigned)u << 16);
}

// ---------------------------------------------------------------------------
// Weight prep: Wt1[96][256] = bf16(W1[k][n]); Wt2[64][96] = bf16(W2[k][n])
// ---------------------------------------------------------------------------
__global__ __launch_bounds__(256) void convw_kernel(const float* __restrict__ W1,
                                                    const float* __restrict__ W2,
                                                    unsigned short* __restrict__ Wt1,
                                                    unsigned short* __restrict__ Wt2) {
    int i = blockIdx.x * 256 + threadIdx.x;
    if (i < 96 * 256) {
        int n = i >> 8, k = i & 255;
        Wt1[i] = f2bf(W1[k * 96 + n]);
    } else {
        int j = i - 96 * 256;
        if (j < 64 * 96) {
            int n = j / 96, k = j - n * 96;
            Wt2[j] = f2bf(W2[k * 64 + n]);
        }
    }
}

// ---------------------------------------------------------------------------
// MFMA GEMM: outb[rows][N](bf16) = src[rows][K] @ Wt[N][K]^T
// BM=64 (4 waves x 16 rows), BK=32, mfma_f32_16x16x32_bf16.
// ---------------------------------------------------------------------------
template <int K, int N, bool IN_BF16>
__global__ __launch_bounds__(256) void gemm_mfma_kernel(const void* __restrict__ src_,
                                                        const unsigned short* __restrict__ Wt,
                                                        unsigned short* __restrict__ outb) {
    constexpr int NF = N / 16;          // n-frags
    constexpr int LDA = 40;             // 32 k + 8 pad
    __shared__ unsigned short a_lds[64 * LDA];
    __shared__ unsigned short b_lds[N * LDA];
    const int tid = threadIdx.x;
    const int lane = tid & 63;
    const int w = tid >> 6;
    const int row0 = blockIdx.x * 64;
    const int fr = lane & 15;
    const int fk = (lane >> 4) * 8;

    float4v acc[NF];
    #pragma unroll
    for (int nn = 0; nn < NF; ++nn) acc[nn] = (float4v){0.f, 0.f, 0.f, 0.f};

    const int srow = tid >> 2;
    const int sko  = (tid & 3) * 8;

    for (int k0 = 0; k0 < K; k0 += 32) {
        {
            int grow = row0 + srow;
            short8 s = (short8){0, 0, 0, 0, 0, 0, 0, 0};
            if (grow < N_NODES) {
                if constexpr (IN_BF16) {
                    const unsigned short* src = (const unsigned short*)src_;
                    s = *reinterpret_cast<const short8*>(&src[(size_t)grow * K + k0 + sko]);
                } else {
                    const float* src = (const float*)src_;
                    const float4* p = reinterpret_cast<const float4*>(&src[(size_t)grow * K + k0 + sko]);
                    float4 v0 = p[0], v1 = p[1];
                    s[0] = (short)f2bf(v0.x); s[1] = (short)f2bf(v0.y);
                    s[2] = (short)f2bf(v0.z); s[3] = (short)f2bf(v0.w);
                    s[4] = (short)f2bf(v1.x); s[5] = (short)f2bf(v1.y);
                    s[6] = (short)f2bf(v1.z); s[7] = (short)f2bf(v1.w);
                }
            }
            *reinterpret_cast<short8*>(&a_lds[srow * LDA + sko]) = s;
        }
        for (int c = tid; c < N * 4; c += 256) {
            int n = c >> 2, ko = (c & 3) * 8;
            short8 s = *reinterpret_cast<const short8*>(&Wt[(size_t)n * K + k0 + ko]);
            *reinterpret_cast<short8*>(&b_lds[n * LDA + ko]) = s;
        }
        __syncthreads();
        short8 af = *reinterpret_cast<short8*>(&a_lds[(w * 16 + fr) * LDA + fk]);
        #pragma unroll
        for (int nn = 0; nn < NF; ++nn) {
            short8 bf = *reinterpret_cast<short8*>(&b_lds[(nn * 16 + fr) * LDA + fk]);
            acc[nn] = __builtin_amdgcn_mfma_f32_16x16x32_bf16(af, bf, acc[nn], 0, 0, 0);
        }
        __syncthreads();
    }
    const int orow_base = row0 + w * 16 + (lane >> 4) * 4;
    const int ocol = lane & 15;
    #pragma unroll
    for (int nn = 0; nn < NF; ++nn) {
        #pragma unroll
        for (int r = 0; r < 4; ++r) {
            int grow = orow_base + r;
            if (grow < N_NODES) outb[(size_t)grow * N + nn * 16 + ocol] = f2bf(acc[nn][r]);
        }
    }
}

// ---------------------------------------------------------------------------
// CSR build step 1: histogram of dst
// ---------------------------------------------------------------------------
__global__ __launch_bounds__(256) void hist_kernel(const int* __restrict__ dstv,
                                                   int* __restrict__ cnt) {
    int e = blockIdx.x * 256 + threadIdx.x;
    if (e < N_EDGES) atomicAdd(&cnt[dstv[e]], 1);
}

// ---------------------------------------------------------------------------
// Multi-block exclusive scan of cnt[50000] -> off[50001].
// ---------------------------------------------------------------------------
__global__ __launch_bounds__(256) void scan1_kernel(const int* __restrict__ cnt,
                                                    int* __restrict__ bsum) {
    __shared__ int red[256];
    const int t = threadIdx.x;
    const int i = blockIdx.x * 256 + t;
    red[t] = (i < N_NODES) ? cnt[i] : 0;
    __syncthreads();
    #pragma unroll
    for (int d = 128; d > 0; d >>= 1) {
        if (t < d) red[t] += red[t + d];
        __syncthreads();
    }
    if (t == 0) bsum[blockIdx.x] = red[0];
}

__global__ __launch_bounds__(256) void scan2_kernel(int* __restrict__ bsum) {
    __shared__ int sh[256];
    const int t = threadIdx.x;
    int v = (t < SCAN_NBLK) ? bsum[t] : 0;
    sh[t] = v;
    __syncthreads();
    #pragma unroll
    for (int d = 1; d < 256; d <<= 1) {
        int u = (t >= d) ? sh[t - d] : 0;
        __syncthreads();
        sh[t] += u;
        __syncthreads();
    }
    if (t < SCAN_NBLK) bsum[t] = sh[t] - v;
}

__global__ __launch_bounds__(256) void scan3_kernel(const int* __restrict__ cnt,
                                                    const int* __restrict__ bsum,
                                                    int* __restrict__ off) {
    __shared__ int sh[256];
    const int t = threadIdx.x;
    const int i = blockIdx.x * 256 + t;
    int v = (i < N_NODES) ? cnt[i] : 0;
    sh[t] = v;
    __syncthreads();
    #pragma unroll
    for (int d = 1; d < 256; d <<= 1) {
        int u = (t >= d) ? sh[t - d] : 0;
        __syncthreads();
        sh[t] += u;
        __syncthreads();
    }
    int excl = sh[t] - v + bsum[blockIdx.x];
    if (i < N_NODES) off[i] = excl;
    if (i == N_NODES - 1) off[N_NODES] = excl + v;
}

// ---------------------------------------------------------------------------
// Bucket cursor init: gcur[b] = off[b*128] (bucket regions of the final CSR).
// ---------------------------------------------------------------------------
__global__ __launch_bounds__(256) void binit_kernel(const int* __restrict__ off,
                                                    int* __restrict__ gcur) {
    int b = blockIdx.x * 256 + threadIdx.x;
    if (b < NBKT) gcur[b] = off[min(b << 7, N_NODES)];
}

// ---------------------------------------------------------------------------
// Sort pass 1: bucket edges by dst>>7 into scratch (int2: dst, payload).
// Per block: LDS histogram + one global atomicAdd per bucket -> per-block
// contiguous runs, so scratch lines are written by at most ~2 blocks.
// ---------------------------------------------------------------------------
__global__ __launch_bounds__(256) void bucket1_kernel(const int* __restrict__ srcv,
                                                      const int* __restrict__ dstv,
                                                      const float* __restrict__ wv,
                                                      int* __restrict__ gcur,
                                                      int2* __restrict__ scratch) {
    __shared__ int lhist[NBKT];
    __shared__ int gb[NBKT];
    const int t = threadIdx.x;
    for (int i = t; i < NBKT; i += 256) lhist[i] = 0;
    __syncthreads();
    const int base = blockIdx.x * 4096;
    int rank[16], bkt[16], dst[16];
    unsigned pay[16];
    #pragma unroll
    for (int i = 0; i < 16; ++i) {
        int e = base + t + i * 256;
        if (e < N_EDGES) {
            int d = dstv[e];
            dst[i] = d;
            bkt[i] = d >> 7;
            unsigned w15 = __float2uint_rn(wv[e] * 32768.0f);
            if (w15 > 32767u) w15 = 32767u;
            pay[i] = ((unsigned)srcv[e] << 15) | w15;
            rank[i] = atomicAdd(&lhist[bkt[i]], 1);
        } else {
            bkt[i] = -1;
        }
    }
    __syncthreads();
    for (int b = t; b < NBKT; b += 256) {
        int c = lhist[b];
        gb[b] = (c > 0) ? atomicAdd(&gcur[b], c) : 0;
    }
    __syncthreads();
    #pragma unroll
    for (int i = 0; i < 16; ++i) {
        if (bkt[i] >= 0)
            scratch[gb[bkt[i]] + rank[i]] = make_int2(dst[i], (int)pay[i]);
    }
}

// ---------------------------------------------------------------------------
// Sort pass 2: one block per bucket; rank by exact dst via 128-entry LDS
// histogram; write payloads into the bucket's contiguous ewq region.
// ---------------------------------------------------------------------------
__global__ __launch_bounds__(256) void bucket2_kernel(const int2* __restrict__ scratch,
                                                      const int* __restrict__ off,
                                                      unsigned* __restrict__ ewq) {
    __shared__ int dhist[128];
    __shared__ int offl[128];
    const int t = threadIdx.x;
    const int b = blockIdx.x;
    const int d0 = b << 7;
    const int nd = min(128, N_NODES - d0);
    if (t < 128) {
        dhist[t] = 0;
        offl[t] = (t < nd) ? off[d0 + t] : 0;
    }
    __syncthreads();
    const int s0 = off[d0];
    const int s1 = off[min(d0 + 128, N_NODES)];
    for (int i = s0 + t; i < s1; i += 256) {
        int2 e = scratch[i];
        int dl = e.x & 127;
        int r = atomicAdd(&dhist[dl], 1);
        ewq[offl[dl] + r] = (unsigned)e.y;
    }
}

// ---------------------------------------------------------------------------
// Gather aggregation (bf16 support table, packed 4B edges), 4x-unrolled.
// ---------------------------------------------------------------------------
template <int DIM, bool OUT_BF16>
__global__ __launch_bounds__(256) void gather_agg_kernel(const unsigned short* __restrict__ supb,
                                                         const int* __restrict__ off,
                                                         const unsigned* __restrict__ ewq,
                                                         const float* __restrict__ bias,
                                                         void* __restrict__ outp) {
    const int NQ = DIM / 4;
    const float kInv = 1.0f / 32768.0f;
    unsigned gid = blockIdx.x * 256u + threadIdx.x;
    if (gid >= (unsigned)N_NODES * NQ) return;
    unsigned n = gid / NQ;
    unsigned q = gid - n * NQ;
    const int e0 = off[n], e1 = off[n + 1];
    float4 a0 = make_float4(0.f, 0.f, 0.f, 0.f);
    float4 a1 = make_float4(0.f, 0.f, 0.f, 0.f);
    float4 a2 = make_float4(0.f, 0.f, 0.f, 0.f);
    float4 a3 = make_float4(0.f, 0.f, 0.f, 0.f);
    int e = e0;
    for (; e + 4 <= e1; e += 4) {
        unsigned p0 = ewq[e];
        unsigned p1 = ewq[e + 1];
        unsigned p2 = ewq[e + 2];
        unsigned p3 = ewq[e + 3];
        ushort4 u0 = *reinterpret_cast<const ushort4*>(&supb[(size_t)(p0 >> 15) * DIM + q * 4]);
        ushort4 u1 = *reinterpret_cast<const ushort4*>(&supb[(size_t)(p1 >> 15) * DIM + q * 4]);
        ushort4 u2 = *reinterpret_cast<const ushort4*>(&supb[(size_t)(p2 >> 15) * DIM + q * 4]);
        ushort4 u3 = *reinterpret_cast<const ushort4*>(&supb[(size_t)(p3 >> 15) * DIM + q * 4]);
        float w0 = (float)(p0 & 32767u) * kInv;
        float w1 = (float)(p1 & 32767u) * kInv;
        float w2 = (float)(p2 & 32767u) * kInv;
        float w3 = (float)(p3 & 32767u) * kInv;
        a0.x += bf2f(u0.x) * w0; a0.y += bf2f(u0.y) * w0;
        a0.z += bf2f(u0.z) * w0; a0.w += bf2f(u0.w) * w0;
        a1.x += bf2f(u1.x) * w1; a1.y += bf2f(u1.y) * w1;
        a1.z += bf2f(u1.z) * w1; a1.w += bf2f(u1.w) * w1;
        a2.x += bf2f(u2.x) * w2; a2.y += bf2f(u2.y) * w2;
        a2.z += bf2f(u2.z) * w2; a2.w += bf2f(u2.w) * w2;
        a3.x += bf2f(u3.x) * w3; a3.y += bf2f(u3.y) * w3;
        a3.z += bf2f(u3.z) * w3; a3.w += bf2f(u3.w) * w3;
    }
    for (; e < e1; ++e) {
        unsigned p = ewq[e];
        float w = (float)(p & 32767u) * kInv;
        ushort4 u = *reinterpret_cast<const ushort4*>(&supb[(size_t)(p >> 15) * DIM + q * 4]);
        a0.x += bf2f(u.x) * w; a0.y += bf2f(u.y) * w;
        a0.z += bf2f(u.z) * w; a0.w += bf2f(u.w) * w;
    }
    a0.x += a1.x + a2.x + a3.x;
    a0.y += a1.y + a2.y + a3.y;
    a0.z += a1.z + a2.z + a3.z;
    a0.w += a1.w + a2.w + a3.w;
    const float4 bb = *reinterpret_cast<const float4*>(&bias[q * 4]);
    a0.x = fmaxf(a0.x + bb.x, 0.f);
    a0.y = fmaxf(a0.y + bb.y, 0.f);
    a0.z = fmaxf(a0.z + bb.z, 0.f);
    a0.w = fmaxf(a0.w + bb.w, 0.f);
    if (OUT_BF16) {
        ushort4 o;
        o.x = f2bf(a0.x); o.y = f2bf(a0.y); o.z = f2bf(a0.z); o.w = f2bf(a0.w);
        *reinterpret_cast<ushort4*>(&((unsigned short*)outp)[(size_t)n * DIM + q * 4]) = o;
    } else {
        *reinterpret_cast<float4*>(&((float*)outp)[(size_t)n * DIM + q * 4]) = a0;
    }
}

// ---------------------------------------------------------------------------
// Column-sum of h2 (f32, already bias+relu'd) over all nodes -> pooled[64]
// ---------------------------------------------------------------------------
__global__ __launch_bounds__(256) void colsum_kernel(const float* __restrict__ h2,
                                                     float* __restrict__ pooled) {
    __shared__ float red[4][64];
    const int t = threadIdx.x;
    const int c = t & 63, r = t >> 6;
    float s = 0.f;
    const int base = blockIdx.x * 256;
    for (int i = r; i < 256; i += 4) {
        int n = base + i;
        if (n < N_NODES) s += h2[(size_t)n * 64 + c];
    }
    red[r][c] = s;
    __syncthreads();
    if (r == 0) {
        float v = red[0][c] + red[1][c] + red[2][c] + red[3][c];
        unsafeAtomicAdd(&pooled[c], v);
    }
}

// ---------------------------------------------------------------------------
// Final head: selu(pooled/N) + 0.5*(sub_fea @ fc_w^T + fc_b) -> log_softmax
// ---------------------------------------------------------------------------
__global__ void final_kernel(const float* __restrict__ pooled,
                             const float* __restrict__ sub_fea,
                             const float* __restrict__ fc_w,
                             const float* __restrict__ fc_b,
                             float* __restrict__ out) {
    const int c = threadIdx.x;  // 0..63
    float p = pooled[c] * (1.0f / (float)N_NODES);
    const float kScale = 1.0507009873554805f;
    const float kAlpha = 1.6732632423543772f;
    float se = (p > 0.f) ? kScale * p : kScale * kAlpha * (expf(p) - 1.f);
    float xe = fc_b[c];
    for (int k = 0; k < 128; ++k) xe += sub_fea[k] * fc_w[c * 128 + k];
    float v = se + 0.5f * xe;
    float m = v;
    #pragma unroll
    for (int off = 32; off >= 1; off >>= 1) m = fmaxf(m, __shfl_xor(m, off));
    float ex = expf(v - m);
    float ss = ex;
    #pragma unroll
    for (int off = 32; off >= 1; off >>= 1) ss += __shfl_xor(ss, off);
    out[c] = v - m - logf(ss);
}

// ---------------------------------------------------------------------------
extern "C" void kernel_launch(void* const* d_in, const int* in_sizes, int n_in,
                              void* d_out, int out_size, void* d_ws, size_t ws_size,
                              hipStream_t stream) {
    const float* x       = (const float*)d_in[0];
    const int*   ei      = (const int*)d_in[1];   // [2][E]: src row 0, dst row 1
    const float* ew      = (const float*)d_in[2];
    const float* sub_fea = (const float*)d_in[3];
    const float* W1      = (const float*)d_in[4];
    const float* b1      = (const float*)d_in[5];
    const float* W2      = (const float*)d_in[6];
    const float* b2      = (const float*)d_in[7];
    const float* fc_w    = (const float*)d_in[8];
    const float* fc_b    = (const float*)d_in[9];
    float* out = (float*)d_out;

    // Workspace layout (bytes).
    char* base = (char*)d_ws;
    unsigned short* A   = (unsigned short*)(base);              // support bf16, 9.6 MB
    char*  Bb    = base + 9600000;                              // h1 bf16 / h2 f32, 12.8 MB
    float* pooled = (float*)(base + 22400000);                  // 64 floats
    int*   off   = (int*)(base + 22400512);                     // 50001 ints
    int*   cnt   = (int*)(base + 22601216);                     // 50000 ints
    int*   bsum  = (int*)(base + 22801920);                     // 256 ints
    int*   gcur  = (int*)(base + 22803968);                     // 512 ints
    unsigned* ewq = (unsigned*)(base + 22806016);               // 800000 u32 (3.2 MB)
    int2*  scratch = (int2*)(base + 26006016);                  // 800000 int2 (6.4 MB)
    unsigned short* Wt1 = (unsigned short*)(base + 32406016);   // 96*256 bf16
    unsigned short* Wt2 = (unsigned short*)(base + 32455168);   // 64*96 bf16

    const int* srcv = ei;
    const int* dstv = ei + N_EDGES;

    // ---- prep: weights -> bf16 transposed ----
    convw_kernel<<<(96 * 256 + 64 * 96 + 255) / 256, 256, 0, stream>>>(W1, W2, Wt1, Wt2);

    // ---- CSR build: hist + scan + 2-pass bucket sort ----
    hipMemsetAsync(cnt, 0, N_NODES * 4, stream);
    hipMemsetAsync(pooled, 0, 64 * 4, stream);
    hist_kernel<<<(N_EDGES + 255) / 256, 256, 0, stream>>>(dstv, cnt);
    scan1_kernel<<<SCAN_NBLK, 256, 0, stream>>>(cnt, bsum);
    scan2_kernel<<<1, 256, 0, stream>>>(bsum);
    scan3_kernel<<<SCAN_NBLK, 256, 0, stream>>>(cnt, bsum, off);
    binit_kernel<<<2, 256, 0, stream>>>(off, gcur);
    bucket1_kernel<<<(N_EDGES + 4095) / 4096, 256, 0, stream>>>(srcv, dstv, ew, gcur, scratch);
    bucket2_kernel<<<NBKT, 256, 0, stream>>>(scratch, off, ewq);

    // ---- Layer 1: support1 = bf16(x @ W1); h1 = bf16(relu(agg + b1)) ----
    gemm_mfma_kernel<256, 96, false><<<(N_NODES + 63) / 64, 256, 0, stream>>>(x, Wt1, A);
    {
        unsigned total = (unsigned)N_NODES * 24;
        gather_agg_kernel<96, true><<<(total + 255) / 256, 256, 0, stream>>>(
            A, off, ewq, b1, Bb);
    }

    // ---- Layer 2: support2 = bf16(h1 @ W2); h2 = f32 relu(agg + b2) ----
    gemm_mfma_kernel<96, 64, true><<<(N_NODES + 63) / 64, 256, 0, stream>>>(Bb, Wt2, A);
    {
        unsigned total = (unsigned)N_NODES * 16;
        gather_agg_kernel<64, false><<<(total + 255) / 256, 256, 0, stream>>>(
            A, off, ewq, b2, Bb);
    }

    // ---- Pool + head ----
    colsum_kernel<<<(N_NODES + 255) / 256, 256, 0, stream>>>((const float*)Bb, pooled);
    final_kernel<<<1, 64, 0, stream>>>(pooled, sub_fea, fc_w, fc_b, out);
}

// Round 9
// 141.476 us; speedup vs baseline: 2.2526x; 1.2596x over previous
//
#include <hip/hip_runtime.h>
#include <hip/hip_bf16.h>

#define N_NODES 50000
#define N_EDGES 800000
#define NBKT ((N_NODES + 127) / 128)        // 391 coarse buckets (128 dst each)
#define BCAP 4096                           // fixed bucket capacity (mean 2048)

typedef __attribute__((ext_vector_type(8))) short short8;
typedef __attribute__((ext_vector_type(4))) float float4v;

__device__ __forceinline__ unsigned short f2bf(float f) {
    unsigned u = __float_as_uint(f);
    u += 0x7FFF + ((u >> 16) & 1);          // round-to-nearest-even
    return (unsigned short)(u >> 16);
}
__device__ __forceinline__ float bf2f(unsigned short u) {
    return __uint_as_float((unsigned)u << 16);
}

// ---------------------------------------------------------------------------
// Prep: Wt1[96][256]=bf16(W1^T); Wt2[64][96]=bf16(W2^T); zero gcnt + pooled.
// One kernel, 122 blocks.
// ---------------------------------------------------------------------------
__global__ __launch_bounds__(256) void prep_kernel(const float* __restrict__ W1,
                                                   const float* __restrict__ W2,
                                                   unsigned short* __restrict__ Wt1,
                                                   unsigned short* __restrict__ Wt2,
                                                   int* __restrict__ gcnt,
                                                   float* __restrict__ pooled) {
    int i = blockIdx.x * 256 + threadIdx.x;
    if (i < 24576) {                        // 96*256
        int n = i >> 8, k = i & 255;
        Wt1[i] = f2bf(W1[k * 96 + n]);
    } else if (i < 30720) {                 // + 64*96
        int j = i - 24576;
        int n = j / 96, k = j - n * 96;
        Wt2[j] = f2bf(W2[k * 64 + n]);
    } else if (i < 30720 + NBKT) {
        gcnt[i - 30720] = 0;
    } else if (i < 30720 + NBKT + 64) {
        pooled[i - 30720 - NBKT] = 0.f;
    }
}

// ---------------------------------------------------------------------------
// MFMA GEMM: outb[rows][N](bf16) = src[rows][K] @ Wt[N][K]^T
// BM=64 (4 waves x 16 rows), BK=32, mfma_f32_16x16x32_bf16.
// ---------------------------------------------------------------------------
template <int K, int N, bool IN_BF16>
__global__ __launch_bounds__(256) void gemm_mfma_kernel(const void* __restrict__ src_,
                                                        const unsigned short* __restrict__ Wt,
                                                        unsigned short* __restrict__ outb) {
    constexpr int NF = N / 16;
    constexpr int LDA = 40;
    __shared__ unsigned short a_lds[64 * LDA];
    __shared__ unsigned short b_lds[N * LDA];
    const int tid = threadIdx.x;
    const int lane = tid & 63;
    const int w = tid >> 6;
    const int row0 = blockIdx.x * 64;
    const int fr = lane & 15;
    const int fk = (lane >> 4) * 8;

    float4v acc[NF];
    #pragma unroll
    for (int nn = 0; nn < NF; ++nn) acc[nn] = (float4v){0.f, 0.f, 0.f, 0.f};

    const int srow = tid >> 2;
    const int sko  = (tid & 3) * 8;

    for (int k0 = 0; k0 < K; k0 += 32) {
        {
            int grow = row0 + srow;
            short8 s = (short8){0, 0, 0, 0, 0, 0, 0, 0};
            if (grow < N_NODES) {
                if constexpr (IN_BF16) {
                    const unsigned short* src = (const unsigned short*)src_;
                    s = *reinterpret_cast<const short8*>(&src[(size_t)grow * K + k0 + sko]);
                } else {
                    const float* src = (const float*)src_;
                    const float4* p = reinterpret_cast<const float4*>(&src[(size_t)grow * K + k0 + sko]);
                    float4 v0 = p[0], v1 = p[1];
                    s[0] = (short)f2bf(v0.x); s[1] = (short)f2bf(v0.y);
                    s[2] = (short)f2bf(v0.z); s[3] = (short)f2bf(v0.w);
                    s[4] = (short)f2bf(v1.x); s[5] = (short)f2bf(v1.y);
                    s[6] = (short)f2bf(v1.z); s[7] = (short)f2bf(v1.w);
                }
            }
            *reinterpret_cast<short8*>(&a_lds[srow * LDA + sko]) = s;
        }
        for (int c = tid; c < N * 4; c += 256) {
            int n = c >> 2, ko = (c & 3) * 8;
            short8 s = *reinterpret_cast<const short8*>(&Wt[(size_t)n * K + k0 + ko]);
            *reinterpret_cast<short8*>(&b_lds[n * LDA + ko]) = s;
        }
        __syncthreads();
        short8 af = *reinterpret_cast<short8*>(&a_lds[(w * 16 + fr) * LDA + fk]);
        #pragma unroll
        for (int nn = 0; nn < NF; ++nn) {
            short8 bf = *reinterpret_cast<short8*>(&b_lds[(nn * 16 + fr) * LDA + fk]);
            acc[nn] = __builtin_amdgcn_mfma_f32_16x16x32_bf16(af, bf, acc[nn], 0, 0, 0);
        }
        __syncthreads();
    }
    const int orow_base = row0 + w * 16 + (lane >> 4) * 4;
    const int ocol = lane & 15;
    #pragma unroll
    for (int nn = 0; nn < NF; ++nn) {
        #pragma unroll
        for (int r = 0; r < 4; ++r) {
            int grow = orow_base + r;
            if (grow < N_NODES) outb[(size_t)grow * N + nn * 16 + ocol] = f2bf(acc[nn][r]);
        }
    }
}

// ---------------------------------------------------------------------------
// Sort pass 1: bucket edges by dst>>7 into FIXED-CAPACITY scratch regions
// [b*BCAP, b*BCAP+cnt). Per-block LDS hist + one global atomicAdd per bucket.
// gcnt[b] accumulates final bucket counts (no prior CSR needed).
// ---------------------------------------------------------------------------
__global__ __launch_bounds__(256) void bucket1_kernel(const int* __restrict__ srcv,
                                                      const int* __restrict__ dstv,
                                                      const float* __restrict__ wv,
                                                      int* __restrict__ gcnt,
                                                      int2* __restrict__ scratch) {
    __shared__ int lhist[NBKT];
    __shared__ int gb[NBKT];
    const int t = threadIdx.x;
    for (int i = t; i < NBKT; i += 256) lhist[i] = 0;
    __syncthreads();
    const int base = blockIdx.x * 4096;
    int rank[16], bkt[16], dst[16];
    unsigned pay[16];
    #pragma unroll
    for (int i = 0; i < 16; ++i) {
        int e = base + t + i * 256;
        if (e < N_EDGES) {
            int d = dstv[e];
            dst[i] = d;
            bkt[i] = d >> 7;
            unsigned w15 = __float2uint_rn(wv[e] * 32768.0f);
            if (w15 > 32767u) w15 = 32767u;
            pay[i] = ((unsigned)srcv[e] << 15) | w15;
            rank[i] = atomicAdd(&lhist[bkt[i]], 1);
        } else {
            bkt[i] = -1;
        }
    }
    __syncthreads();
    for (int b = t; b < NBKT; b += 256) {
        int c = lhist[b];
        gb[b] = (c > 0) ? atomicAdd(&gcnt[b], c) : 0;
    }
    __syncthreads();
    #pragma unroll
    for (int i = 0; i < 16; ++i) {
        if (bkt[i] >= 0) {
            int pos = gb[bkt[i]] + rank[i];
            if (pos < BCAP)                 // safety; never hit at BCAP=2x mean
                scratch[(size_t)bkt[i] * BCAP + pos] = make_int2(dst[i], (int)pay[i]);
        }
    }
}

// ---------------------------------------------------------------------------
// Bucket-base scan: exclusive scan of gcnt[391] -> bbase; off[N_NODES]=total.
// Single block, 512 threads.
// ---------------------------------------------------------------------------
__global__ __launch_bounds__(512) void bscan_kernel(const int* __restrict__ gcnt,
                                                    int* __restrict__ bbase,
                                                    int* __restrict__ off) {
    __shared__ int sh[512];
    const int t = threadIdx.x;
    int v = (t < NBKT) ? min(gcnt[t], BCAP) : 0;
    sh[t] = v;
    __syncthreads();
    #pragma unroll
    for (int d = 1; d < 512; d <<= 1) {
        int u = (t >= d) ? sh[t - d] : 0;
        __syncthreads();
        sh[t] += u;
        __syncthreads();
    }
    if (t < NBKT) bbase[t] = sh[t] - v;
    if (t == NBKT - 1) off[N_NODES] = sh[t];
}

// ---------------------------------------------------------------------------
// Sort pass 2: one block per bucket. Per-dst hist from slice -> LDS scan ->
// writes off[d0..d0+127] AND final payloads into contiguous ewq region.
// ---------------------------------------------------------------------------
__global__ __launch_bounds__(256) void bucket2_kernel(const int2* __restrict__ scratch,
                                                      const int* __restrict__ gcnt,
                                                      const int* __restrict__ bbase,
                                                      int* __restrict__ off,
                                                      unsigned* __restrict__ ewq) {
    __shared__ int dh[128];
    __shared__ int sx[128];
    __shared__ int dcur[128];
    const int t = threadIdx.x;
    const int b = blockIdx.x;
    const int d0 = b << 7;
    const int cnt = min(gcnt[b], BCAP);
    const size_t sbase = (size_t)b * BCAP;
    const int obase = bbase[b];
    if (t < 128) dh[t] = 0;
    __syncthreads();
    for (int i = t; i < cnt; i += 256)
        atomicAdd(&dh[scratch[sbase + i].x & 127], 1);
    __syncthreads();
    int myc = (t < 128) ? dh[t] : 0;
    if (t < 128) sx[t] = myc;
    __syncthreads();
    #pragma unroll
    for (int d = 1; d < 128; d <<= 1) {
        int u = (t < 128 && t >= d) ? sx[t - d] : 0;
        __syncthreads();
        if (t < 128) sx[t] += u;
        __syncthreads();
    }
    if (t < 128) {
        int excl = obase + sx[t] - myc;
        dcur[t] = excl;
        if (d0 + t < N_NODES) off[d0 + t] = excl;
    }
    __syncthreads();
    for (int i = t; i < cnt; i += 256) {
        int2 e = scratch[sbase + i];
        int pos = atomicAdd(&dcur[e.x & 127], 1);
        ewq[pos] = (unsigned)e.y;
    }
}

// ---------------------------------------------------------------------------
// Gather aggregation (bf16 support table, packed 4B edges), 8x-unrolled MLP.
// ---------------------------------------------------------------------------
template <int DIM, bool OUT_BF16>
__global__ __launch_bounds__(256) void gather_agg_kernel(const unsigned short* __restrict__ supb,
                                                         const int* __restrict__ off,
                                                         const unsigned* __restrict__ ewq,
                                                         const float* __restrict__ bias,
                                                         void* __restrict__ outp) {
    const int NQ = DIM / 4;
    const float kInv = 1.0f / 32768.0f;
    unsigned gid = blockIdx.x * 256u + threadIdx.x;
    if (gid >= (unsigned)N_NODES * NQ) return;
    unsigned n = gid / NQ;
    unsigned q = gid - n * NQ;
    const int e0 = off[n], e1 = off[n + 1];
    float4 acc[8];
    #pragma unroll
    for (int i = 0; i < 8; ++i) acc[i] = make_float4(0.f, 0.f, 0.f, 0.f);
    int e = e0;
    for (; e + 8 <= e1; e += 8) {
        unsigned p[8];
        #pragma unroll
        for (int i = 0; i < 8; ++i) p[i] = ewq[e + i];
        ushort4 u[8];
        #pragma unroll
        for (int i = 0; i < 8; ++i)
            u[i] = *reinterpret_cast<const ushort4*>(&supb[(size_t)(p[i] >> 15) * DIM + q * 4]);
        #pragma unroll
        for (int i = 0; i < 8; ++i) {
            float w = (float)(p[i] & 32767u) * kInv;
            acc[i].x += bf2f(u[i].x) * w;
            acc[i].y += bf2f(u[i].y) * w;
            acc[i].z += bf2f(u[i].z) * w;
            acc[i].w += bf2f(u[i].w) * w;
        }
    }
    for (; e < e1; ++e) {
        unsigned p = ewq[e];
        float w = (float)(p & 32767u) * kInv;
        ushort4 u = *reinterpret_cast<const ushort4*>(&supb[(size_t)(p >> 15) * DIM + q * 4]);
        acc[0].x += bf2f(u.x) * w;
        acc[0].y += bf2f(u.y) * w;
        acc[0].z += bf2f(u.z) * w;
        acc[0].w += bf2f(u.w) * w;
    }
    #pragma unroll
    for (int i = 1; i < 8; ++i) {
        acc[0].x += acc[i].x;
        acc[0].y += acc[i].y;
        acc[0].z += acc[i].z;
        acc[0].w += acc[i].w;
    }
    const float4 bb = *reinterpret_cast<const float4*>(&bias[q * 4]);
    float4 r;
    r.x = fmaxf(acc[0].x + bb.x, 0.f);
    r.y = fmaxf(acc[0].y + bb.y, 0.f);
    r.z = fmaxf(acc[0].z + bb.z, 0.f);
    r.w = fmaxf(acc[0].w + bb.w, 0.f);
    if (OUT_BF16) {
        ushort4 o;
        o.x = f2bf(r.x); o.y = f2bf(r.y); o.z = f2bf(r.z); o.w = f2bf(r.w);
        *reinterpret_cast<ushort4*>(&((unsigned short*)outp)[(size_t)n * DIM + q * 4]) = o;
    } else {
        *reinterpret_cast<float4*>(&((float*)outp)[(size_t)n * DIM + q * 4]) = r;
    }
}

// ---------------------------------------------------------------------------
// Column-sum of h2 (f32, already bias+relu'd) over all nodes -> pooled[64]
// ---------------------------------------------------------------------------
__global__ __launch_bounds__(256) void colsum_kernel(const float* __restrict__ h2,
                                                     float* __restrict__ pooled) {
    __shared__ float red[4][64];
    const int t = threadIdx.x;
    const int c = t & 63, r = t >> 6;
    float s = 0.f;
    const int base = blockIdx.x * 256;
    for (int i = r; i < 256; i += 4) {
        int n = base + i;
        if (n < N_NODES) s += h2[(size_t)n * 64 + c];
    }
    red[r][c] = s;
    __syncthreads();
    if (r == 0) {
        float v = red[0][c] + red[1][c] + red[2][c] + red[3][c];
        unsafeAtomicAdd(&pooled[c], v);
    }
}

// ---------------------------------------------------------------------------
// Final head: selu(pooled/N) + 0.5*(sub_fea @ fc_w^T + fc_b) -> log_softmax
// ---------------------------------------------------------------------------
__global__ void final_kernel(const float* __restrict__ pooled,
                             const float* __restrict__ sub_fea,
                             const float* __restrict__ fc_w,
                             const float* __restrict__ fc_b,
                             float* __restrict__ out) {
    const int c = threadIdx.x;  // 0..63
    float p = pooled[c] * (1.0f / (float)N_NODES);
    const float kScale = 1.0507009873554805f;
    const float kAlpha = 1.6732632423543772f;
    float se = (p > 0.f) ? kScale * p : kScale * kAlpha * (expf(p) - 1.f);
    float xe = fc_b[c];
    for (int k = 0; k < 128; ++k) xe += sub_fea[k] * fc_w[c * 128 + k];
    float v = se + 0.5f * xe;
    float m = v;
    #pragma unroll
    for (int off = 32; off >= 1; off >>= 1) m = fmaxf(m, __shfl_xor(m, off));
    float ex = expf(v - m);
    float ss = ex;
    #pragma unroll
    for (int off = 32; off >= 1; off >>= 1) ss += __shfl_xor(ss, off);
    out[c] = v - m - logf(ss);
}

// ---------------------------------------------------------------------------
extern "C" void kernel_launch(void* const* d_in, const int* in_sizes, int n_in,
                              void* d_out, int out_size, void* d_ws, size_t ws_size,
                              hipStream_t stream) {
    const float* x       = (const float*)d_in[0];
    const int*   ei      = (const int*)d_in[1];   // [2][E]: src row 0, dst row 1
    const float* ew      = (const float*)d_in[2];
    const float* sub_fea = (const float*)d_in[3];
    const float* W1      = (const float*)d_in[4];
    const float* b1      = (const float*)d_in[5];
    const float* W2      = (const float*)d_in[6];
    const float* b2      = (const float*)d_in[7];
    const float* fc_w    = (const float*)d_in[8];
    const float* fc_b    = (const float*)d_in[9];
    float* out = (float*)d_out;

    // Workspace layout (bytes).
    char* base = (char*)d_ws;
    unsigned short* A   = (unsigned short*)(base);              // support bf16, 9.6 MB
    char*  Bb    = base + 9600000;                              // h1 bf16 / h2 f32, 12.8 MB
    float* pooled = (float*)(base + 22400000);                  // 64 f32
    int*   off   = (int*)(base + 22400512);                     // 50001 ints
    int*   gcnt  = (int*)(base + 22600704);                     // 391 ints
    int*   bbase = (int*)(base + 22602752);                     // 391 ints
    unsigned* ewq = (unsigned*)(base + 22604800);               // 800000 u32 (3.2 MB)
    int2*  scratch = (int2*)(base + 25804800);                  // 391*4096 int2 (12.8 MB)
    unsigned short* Wt1 = (unsigned short*)(base + 38617088);   // 96*256 bf16
    unsigned short* Wt2 = (unsigned short*)(base + 38666240);   // 64*96 bf16

    const int* srcv = ei;
    const int* dstv = ei + N_EDGES;

    // ---- prep (weights + zero counters) ----
    prep_kernel<<<122, 256, 0, stream>>>(W1, W2, Wt1, Wt2, gcnt, pooled);

    // ---- edge sort: fixed-cap bucket -> scan -> place (writes off + ewq) ----
    bucket1_kernel<<<(N_EDGES + 4095) / 4096, 256, 0, stream>>>(srcv, dstv, ew, gcnt, scratch);
    bscan_kernel<<<1, 512, 0, stream>>>(gcnt, bbase, off);
    bucket2_kernel<<<NBKT, 256, 0, stream>>>(scratch, gcnt, bbase, off, ewq);

    // ---- Layer 1: support1 = bf16(x @ W1); h1 = bf16(relu(agg + b1)) ----
    gemm_mfma_kernel<256, 96, false><<<(N_NODES + 63) / 64, 256, 0, stream>>>(x, Wt1, A);
    {
        unsigned total = (unsigned)N_NODES * 24;
        gather_agg_kernel<96, true><<<(total + 255) / 256, 256, 0, stream>>>(
            A, off, ewq, b1, Bb);
    }

    // ---- Layer 2: support2 = bf16(h1 @ W2); h2 = f32 relu(agg + b2) ----
    gemm_mfma_kernel<96, 64, true><<<(N_NODES + 63) / 64, 256, 0, stream>>>(Bb, Wt2, A);
    {
        unsigned total = (unsigned)N_NODES * 16;
        gather_agg_kernel<64, false><<<(total + 255) / 256, 256, 0, stream>>>(
            A, off, ewq, b2, Bb);
    }

    // ---- Pool + head ----
    colsum_kernel<<<(N_NODES + 255) / 256, 256, 0, stream>>>((const float*)Bb, pooled);
    final_kernel<<<1, 64, 0, stream>>>(pooled, sub_fea, fc_w, fc_b, out);
}